// Round 1
// baseline (2284.078 us; speedup 1.0000x reference)
//
#include <hip/hip_runtime.h>
#include <hip/hip_bf16.h>
#include <math.h>

#define S_LEN 8192
#define NH 16
#define DH 64
#define BB 2
#define EE 1024

typedef float floatx4 __attribute__((ext_vector_type(4)));

// ---------------------------------------------------------------------------
// Hilbert curve d-index for (x,y) on n x n grid (matches reference _xy2d).
// ---------------------------------------------------------------------------
__device__ inline int hilbert_xy2d(int n, int x, int y) {
  int d = 0;
  for (int s = n >> 1; s > 0; s >>= 1) {
    int rx = (x & s) ? 1 : 0;
    int ry = (y & s) ? 1 : 0;
    d += s * s * ((3 * rx) ^ ry);
    if (ry == 0) {
      if (rx == 1) { x = s - 1 - x; y = s - 1 - y; }
      int t = x; x = y; y = t;
    }
  }
  return d;
}

// ---------------------------------------------------------------------------
// Build the gather table: idx[pos + j*g + i] = pos + perm[i*rate + j].
// One block per segment. Hilbert d-map on a full grid is a bijection, so
// argsort(d) is just the scatter order[d] = cell.
// ---------------------------------------------------------------------------
__global__ void build_idx_kernel(int* __restrict__ idx) {
  __shared__ int order[4096];
  __shared__ int perm[4096];
  __shared__ int cnts[256];
  const int seg = blockIdx.x;
  const int posA[4] = {0, 1024, 2048, 4096};
  const int LA[4]   = {1024, 1024, 2048, 4096};
  const int pos = posA[seg];
  const int L = LA[seg];
  const int lr = seg;  // log2(rate) == segment index: rates 1,2,4,8
  const int side  = (L <= 1024) ? 32 : 64;
  const int lside = (L <= 1024) ? 5 : 6;
  const int cells = side * side;
  const int tid = threadIdx.x;

  for (int c = tid; c < cells; c += 256) {
    int x = c & (side - 1);
    int y = c >> lside;
    order[hilbert_xy2d(side, x, y)] = c;
  }
  __syncthreads();

  if (L == cells) {
    for (int t = tid; t < L; t += 256) perm[t] = order[t];
  } else {
    // cells=4096, L=2048: stable compaction of order[] entries < L
    const int per = cells >> 8;  // 16
    const int base = tid * per;
    int cnt = 0;
    for (int u = 0; u < per; ++u) cnt += (order[base + u] < L) ? 1 : 0;
    cnts[tid] = cnt;
    __syncthreads();
    if (tid == 0) {
      int s = 0;
      for (int i = 0; i < 256; ++i) { int c0 = cnts[i]; cnts[i] = s; s += c0; }
    }
    __syncthreads();
    int r = cnts[tid];
    for (int u = 0; u < per; ++u) {
      int o = order[base + u];
      if (o < L) perm[r++] = o;
    }
  }
  __syncthreads();

  const int g = L >> lr;
  const int rm = (1 << lr) - 1;
  for (int t = tid; t < L; t += 256) {
    int j = t & rm;
    int i = t >> lr;
    idx[pos + j * g + i] = pos + perm[t];
  }
}

// ---------------------------------------------------------------------------
// FP32 GEMM: C = A(M x K) @ B(N x K)^T + bias.  128x64 tile, 256 threads,
// 8x4 accumulator per thread. MODE 0: scatter-store into q/k/v (B,H,S,D)
// layout (n -> which,h,d).  MODE 1: plain row-major C.
// ---------------------------------------------------------------------------
template<int MODE>
__global__ __launch_bounds__(256) void gemm_kernel(
    const float* __restrict__ A, const float* __restrict__ Bw,
    const float* __restrict__ bias,
    float* __restrict__ C0, float* __restrict__ C1, float* __restrict__ C2,
    int M, int N, int K) {
  __shared__ float As[16][132];
  __shared__ float Bs[16][68];
  const int tid = threadIdx.x;
  const int tx = tid & 15;
  const int ty = tid >> 4;
  const int bm0 = blockIdx.x * 128;
  const int bn0 = blockIdx.y * 64;

  float acc[8][4];
#pragma unroll
  for (int i = 0; i < 8; ++i)
#pragma unroll
    for (int j = 0; j < 4; ++j) acc[i][j] = 0.f;

  const int ar = tid >> 1;
  const int ac = (tid & 1) * 8;
  const int br = tid >> 2;
  const int bc = (tid & 3) * 4;
  const float* Arow = A + (size_t)(bm0 + ar) * K + ac;
  const float* Brow = Bw + (size_t)(bn0 + br) * K + bc;

  for (int k0 = 0; k0 < K; k0 += 16) {
    floatx4 av0 = *(const floatx4*)(Arow + k0);
    floatx4 av1 = *(const floatx4*)(Arow + k0 + 4);
    floatx4 bv  = *(const floatx4*)(Brow + k0);
    __syncthreads();  // previous iteration's reads complete
#pragma unroll
    for (int u = 0; u < 4; ++u) {
      As[ac + u][ar]     = av0[u];
      As[ac + 4 + u][ar] = av1[u];
      Bs[bc + u][br]     = bv[u];
    }
    __syncthreads();
#pragma unroll
    for (int kk = 0; kk < 16; ++kk) {
      floatx4 a0 = *(const floatx4*)&As[kk][ty * 8];
      floatx4 a1 = *(const floatx4*)&As[kk][ty * 8 + 4];
      floatx4 b  = *(const floatx4*)&Bs[kk][tx * 4];
#pragma unroll
      for (int i = 0; i < 4; ++i)
#pragma unroll
        for (int j = 0; j < 4; ++j) {
          acc[i][j]     += a0[i] * b[j];
          acc[4 + i][j] += a1[i] * b[j];
        }
    }
  }

  float bvj[4];
#pragma unroll
  for (int j = 0; j < 4; ++j) bvj[j] = bias[bn0 + tx * 4 + j];

  if (MODE == 0) {
    const int which = bn0 >> 10;
    const int h = (bn0 >> 6) & 15;
    float* dst = (which == 0) ? C0 : (which == 1) ? C1 : C2;
#pragma unroll
    for (int i = 0; i < 8; ++i) {
      int gm = bm0 + ty * 8 + i;
      int b = gm >> 13;
      int s = gm & 8191;
      floatx4 o;
#pragma unroll
      for (int j = 0; j < 4; ++j) o[j] = acc[i][j] + bvj[j];
      *(floatx4*)(dst + ((size_t)(b * NH + h) * S_LEN + s) * DH + tx * 4) = o;
    }
  } else {
#pragma unroll
    for (int i = 0; i < 8; ++i) {
      int gm = bm0 + ty * 8 + i;
      floatx4 o;
#pragma unroll
      for (int j = 0; j < 4; ++j) o[j] = acc[i][j] + bvj[j];
      *(floatx4*)(C0 + (size_t)gm * N + bn0 + tx * 4) = o;
    }
  }
}

// ---------------------------------------------------------------------------
// FP32 attention over one 64-query chunk of one (b, h, group).
// Q rows gathered via idx, K/V tiles gathered via idx, full softmax over the
// group (online), scatter output into (B, S, E) layout for the final GEMM.
// 256 threads: tx = kc/4 or d/4 column group, ty = q-row group (4 rows each).
// ---------------------------------------------------------------------------
__global__ __launch_bounds__(256) void attn_kernel(
    const float* __restrict__ q, const float* __restrict__ k,
    const float* __restrict__ v, const int* __restrict__ idx,
    float* __restrict__ out) {
  __shared__ float Qs[64][68];  // Qs[d][qr]   (transposed, scaled)
  __shared__ float KP[64][68];  // Kt[d][kc] during S phase, then P[kc][qr]
  __shared__ float Vs[64][68];  // Vs[kc][d]

  const int bid = blockIdx.x;
  const int bh = bid >> 7;
  const int c = bid & 127;
  const int b = bh >> 4;
  const int h = bh & 15;
  int idx_base, qoff, g;
  if (c < 16) { idx_base = 0; qoff = c * 64; g = 1024; }
  else {
    int t = c - 16;
    idx_base = 1024 + (t >> 3) * 512;
    qoff = (t & 7) * 64;
    g = 512;
  }

  const size_t bh_off = (size_t)(b * NH + h) * S_LEN * DH;
  const float* qb = q + bh_off;
  const float* kb = k + bh_off;
  const float* vb = v + bh_off;

  const int tid = threadIdx.x;
  const int tx = tid & 15;
  const int ty = tid >> 4;
  const int sr = tid >> 2;        // staging row 0..63
  const int scb = (tid & 3) * 16; // staging col base

  // stage Q (scaled by 1/sqrt(Dh)), transposed
  {
    int grow = idx[idx_base + qoff + sr];
    const float* src = qb + (size_t)grow * DH + scb;
#pragma unroll
    for (int u = 0; u < 4; ++u) {
      floatx4 val = *(const floatx4*)(src + u * 4);
#pragma unroll
      for (int ii = 0; ii < 4; ++ii) Qs[scb + u * 4 + ii][sr] = val[ii] * 0.125f;
    }
  }

  float m[4], l[4], o[4][4];
#pragma unroll
  for (int i = 0; i < 4; ++i) {
    m[i] = -1e30f; l[i] = 0.f;
#pragma unroll
    for (int j = 0; j < 4; ++j) o[i][j] = 0.f;
  }

  const int ntiles = g >> 6;
  for (int kt = 0; kt < ntiles; ++kt) {
    int grow = idx[idx_base + kt * 64 + sr];
    const float* ksrc = kb + (size_t)grow * DH + scb;
    const float* vsrc = vb + (size_t)grow * DH + scb;
    __syncthreads();  // previous tile's PV reads of KP/Vs done (also covers Q stage)
#pragma unroll
    for (int u = 0; u < 4; ++u) {
      floatx4 kv = *(const floatx4*)(ksrc + u * 4);
      floatx4 vv = *(const floatx4*)(vsrc + u * 4);
#pragma unroll
      for (int ii = 0; ii < 4; ++ii) KP[scb + u * 4 + ii][sr] = kv[ii];
      *(floatx4*)&Vs[sr][scb + u * 4] = vv;
    }
    __syncthreads();

    // S = (Q*scale) @ K^T, 4x4 per thread
    float sc_[4][4];
#pragma unroll
    for (int i = 0; i < 4; ++i)
#pragma unroll
      for (int j = 0; j < 4; ++j) sc_[i][j] = 0.f;
#pragma unroll 8
    for (int d = 0; d < 64; ++d) {
      floatx4 qv = *(const floatx4*)&Qs[d][ty * 4];
      floatx4 kv = *(const floatx4*)&KP[d][tx * 4];
#pragma unroll
      for (int i = 0; i < 4; ++i)
#pragma unroll
        for (int j = 0; j < 4; ++j) sc_[i][j] += qv[i] * kv[j];
    }

    // online softmax update (row reductions across the 16 tx lanes)
#pragma unroll
    for (int i = 0; i < 4; ++i) {
      float mx = fmaxf(fmaxf(sc_[i][0], sc_[i][1]), fmaxf(sc_[i][2], sc_[i][3]));
#pragma unroll
      for (int w = 1; w < 16; w <<= 1) mx = fmaxf(mx, __shfl_xor(mx, w, 16));
      float mn = fmaxf(m[i], mx);
      float rescale = __expf(m[i] - mn);
      float su = 0.f;
#pragma unroll
      for (int j = 0; j < 4; ++j) { sc_[i][j] = __expf(sc_[i][j] - mn); su += sc_[i][j]; }
#pragma unroll
      for (int w = 1; w < 16; w <<= 1) su += __shfl_xor(su, w, 16);
      l[i] = l[i] * rescale + su;
      m[i] = mn;
#pragma unroll
      for (int j = 0; j < 4; ++j) o[i][j] *= rescale;
    }
    __syncthreads();  // all S-phase reads of KP done before overwriting with P

    // write P transposed: KP[kc][qr]
#pragma unroll
    for (int i = 0; i < 4; ++i)
#pragma unroll
      for (int j = 0; j < 4; ++j)
        KP[tx * 4 + j][ty * 4 + i] = sc_[i][j];
    __syncthreads();

    // O += P @ V
#pragma unroll 8
    for (int kc = 0; kc < 64; ++kc) {
      floatx4 pv = *(const floatx4*)&KP[kc][ty * 4];
      floatx4 vv = *(const floatx4*)&Vs[kc][tx * 4];
#pragma unroll
      for (int i = 0; i < 4; ++i)
#pragma unroll
        for (int j = 0; j < 4; ++j) o[i][j] += pv[i] * vv[j];
    }
  }

  // normalize + scatter to (B, S, E)
#pragma unroll
  for (int i = 0; i < 4; ++i) {
    float inv = 1.f / l[i];
    int grow = idx[idx_base + qoff + ty * 4 + i];
    floatx4 ov;
#pragma unroll
    for (int j = 0; j < 4; ++j) ov[j] = o[i][j] * inv;
    *(floatx4*)(out + ((size_t)b * S_LEN + grow) * EE + h * DH + tx * 4) = ov;
  }
}

// ---------------------------------------------------------------------------
extern "C" void kernel_launch(void* const* d_in, const int* in_sizes, int n_in,
                              void* d_out, int out_size, void* d_ws, size_t ws_size,
                              hipStream_t stream) {
  const float* x     = (const float*)d_in[0];
  const float* w_qkv = (const float*)d_in[1];
  const float* b_qkv = (const float*)d_in[2];
  const float* w_out = (const float*)d_in[3];
  const float* b_out = (const float*)d_in[4];
  float* outp = (float*)d_out;
  float* ws = (float*)d_ws;

  const size_t per = (size_t)BB * NH * S_LEN * DH;  // 16,777,216 floats
  float* kbuf = ws;
  float* vbuf = ws + per;
  float* attn = ws + 2 * per;
  int*   idx  = (int*)(ws + 3 * per);
  float* qbuf = outp;  // q lives in d_out until the final GEMM overwrites it

  build_idx_kernel<<<4, 256, 0, stream>>>(idx);
  gemm_kernel<0><<<dim3(128, 48), 256, 0, stream>>>(
      x, w_qkv, b_qkv, qbuf, kbuf, vbuf, BB * S_LEN, 3 * EE, EE);
  attn_kernel<<<4096, 256, 0, stream>>>(qbuf, kbuf, vbuf, idx, attn);
  gemm_kernel<1><<<dim3(128, 16), 256, 0, stream>>>(
      attn, w_out, b_out, outp, nullptr, nullptr, BB * S_LEN, EE, EE);
}

// Round 2
// 1167.588 us; speedup vs baseline: 1.9562x; 1.9562x over previous
//
#include <hip/hip_runtime.h>
#include <hip/hip_bf16.h>
#include <math.h>

#define S_LEN 8192
#define NH 16
#define DH 64
#define BB 2
#define EE 1024

typedef float floatx4 __attribute__((ext_vector_type(4)));
typedef float f32x4 __attribute__((ext_vector_type(4)));
typedef short bf16x8 __attribute__((ext_vector_type(8)));
typedef unsigned short u16x4 __attribute__((ext_vector_type(4)));

__device__ inline unsigned short f2bf(float x) {
  unsigned int u = __builtin_bit_cast(unsigned int, x);
  u += 0x7FFFu + ((u >> 16) & 1u);
  return (unsigned short)(u >> 16);
}
__device__ inline float bf2f(unsigned short h) {
  return __builtin_bit_cast(float, (unsigned int)h << 16);
}

__device__ inline void async_copy16(void* lds, const void* g) {
  __builtin_amdgcn_global_load_lds(
      (const __attribute__((address_space(1))) void*)g,
      (__attribute__((address_space(3))) void*)lds, 16, 0, 0);
}

// ---------------------------------------------------------------------------
// Hilbert curve d-index (matches reference _xy2d).
// ---------------------------------------------------------------------------
__device__ inline int hilbert_xy2d(int n, int x, int y) {
  int d = 0;
  for (int s = n >> 1; s > 0; s >>= 1) {
    int rx = (x & s) ? 1 : 0;
    int ry = (y & s) ? 1 : 0;
    d += s * s * ((3 * rx) ^ ry);
    if (ry == 0) {
      if (rx == 1) { x = s - 1 - x; y = s - 1 - y; }
      int t = x; x = y; y = t;
    }
  }
  return d;
}

__global__ void build_idx_kernel(int* __restrict__ idx) {
  __shared__ int order[4096];
  __shared__ int perm[4096];
  __shared__ int cnts[256];
  const int seg = blockIdx.x;
  const int posA[4] = {0, 1024, 2048, 4096};
  const int LA[4]   = {1024, 1024, 2048, 4096};
  const int pos = posA[seg];
  const int L = LA[seg];
  const int lr = seg;  // log2(rate)
  const int side  = (L <= 1024) ? 32 : 64;
  const int lside = (L <= 1024) ? 5 : 6;
  const int cells = side * side;
  const int tid = threadIdx.x;

  for (int c = tid; c < cells; c += 256) {
    int x = c & (side - 1);
    int y = c >> lside;
    order[hilbert_xy2d(side, x, y)] = c;
  }
  __syncthreads();

  if (L == cells) {
    for (int t = tid; t < L; t += 256) perm[t] = order[t];
  } else {
    const int per = cells >> 8;  // 16
    const int base = tid * per;
    int cnt = 0;
    for (int u = 0; u < per; ++u) cnt += (order[base + u] < L) ? 1 : 0;
    cnts[tid] = cnt;
    __syncthreads();
    if (tid == 0) {
      int s = 0;
      for (int i = 0; i < 256; ++i) { int c0 = cnts[i]; cnts[i] = s; s += c0; }
    }
    __syncthreads();
    int r = cnts[tid];
    for (int u = 0; u < per; ++u) {
      int o = order[base + u];
      if (o < L) perm[r++] = o;
    }
  }
  __syncthreads();

  const int g = L >> lr;
  const int rm = (1 << lr) - 1;
  for (int t = tid; t < L; t += 256) {
    int j = t & rm;
    int i = t >> lr;
    idx[pos + j * g + i] = pos + perm[t];
  }
}

// ---------------------------------------------------------------------------
// Split fp32 -> bf16 hi + bf16 lo (residual). 8 elems/thread.
// ---------------------------------------------------------------------------
__global__ __launch_bounds__(256) void split_kernel(
    const float* __restrict__ in, unsigned short* __restrict__ hi,
    unsigned short* __restrict__ lo, int n) {
  int base = (blockIdx.x * 256 + threadIdx.x) * 8;
  if (base >= n) return;
  floatx4 v0 = *(const floatx4*)(in + base);
  floatx4 v1 = *(const floatx4*)(in + base + 4);
  u16x4 h0, h1, l0, l1;
#pragma unroll
  for (int i = 0; i < 4; ++i) {
    unsigned short h = f2bf(v0[i]);
    h0[i] = h; l0[i] = f2bf(v0[i] - bf2f(h));
    unsigned short h2 = f2bf(v1[i]);
    h1[i] = h2; l1[i] = f2bf(v1[i] - bf2f(h2));
  }
  *(u16x4*)(hi + base) = h0;
  *(u16x4*)(hi + base + 4) = h1;
  *(u16x4*)(lo + base) = l0;
  *(u16x4*)(lo + base + 4) = l1;
}

// ---------------------------------------------------------------------------
// bf16x3 split MFMA GEMM: C = A(MxK) @ B(NxK)^T + bias, fp32-accurate.
// 128x128 tile, BK=32, 256 threads (4 waves, 2x2), fragment-linear LDS
// staged via per-lane-source global_load_lds (16B). 48 MFMA / K-step / wave.
// MODE 0: scatter into q/k/v (B,H,S,D). MODE 1: row-major C.
// ---------------------------------------------------------------------------
template<int MODE>
__global__ __launch_bounds__(256) void mgemm_kernel(
    const unsigned short* __restrict__ Ahi, const unsigned short* __restrict__ Alo,
    const unsigned short* __restrict__ Bhi, const unsigned short* __restrict__ Blo,
    const float* __restrict__ bias,
    float* __restrict__ C0, float* __restrict__ C1, float* __restrict__ C2,
    int N, int K) {
  // 4 tiles (Ahi,Alo,Bhi,Blo) x 8 groups x 64 lanes x 8 bf16 = 32 KB
  __shared__ short lds[16384];
  const int tid = threadIdx.x;
  const int lane = tid & 63;
  const int w = tid >> 6;
  const int wr = w >> 1, wc = w & 1;
  const int bm0 = blockIdx.x * 128;
  const int bn0 = blockIdx.y * 128;

  // staging: wave w owns tile w
  const unsigned short* srcbase = (w == 0) ? Ahi : (w == 1) ? Alo
                                 : (w == 2) ? Bhi : Blo;
  const int row0 = (w < 2) ? bm0 : bn0;
  const unsigned short* sp =
      srcbase + (size_t)(row0 + (lane & 15)) * K + (lane >> 4) * 8;
  short* ldst = &lds[w * 4096];

  f32x4 acc[4][4];
#pragma unroll
  for (int m = 0; m < 4; ++m)
#pragma unroll
    for (int n = 0; n < 4; ++n) acc[m][n] = (f32x4)0.f;

  for (int k0 = 0; k0 < K; k0 += 32) {
    __syncthreads();  // previous iteration's LDS reads complete
#pragma unroll
    for (int g = 0; g < 8; ++g)
      async_copy16(ldst + g * 512, sp + (size_t)g * 16 * K + k0);
    __syncthreads();  // staged data visible (vmcnt(0) before barrier)

    bf16x8 ah[4], al[4], bh[4], bl[4];
#pragma unroll
    for (int m = 0; m < 4; ++m) {
      ah[m] = *(const bf16x8*)&lds[0 * 4096 + (wr * 4 + m) * 512 + lane * 8];
      al[m] = *(const bf16x8*)&lds[1 * 4096 + (wr * 4 + m) * 512 + lane * 8];
    }
#pragma unroll
    for (int n = 0; n < 4; ++n) {
      bh[n] = *(const bf16x8*)&lds[2 * 4096 + (wc * 4 + n) * 512 + lane * 8];
      bl[n] = *(const bf16x8*)&lds[3 * 4096 + (wc * 4 + n) * 512 + lane * 8];
    }
#pragma unroll
    for (int m = 0; m < 4; ++m)
#pragma unroll
      for (int n = 0; n < 4; ++n) {
        acc[m][n] = __builtin_amdgcn_mfma_f32_16x16x32_bf16(ah[m], bh[n], acc[m][n], 0, 0, 0);
        acc[m][n] = __builtin_amdgcn_mfma_f32_16x16x32_bf16(ah[m], bl[n], acc[m][n], 0, 0, 0);
        acc[m][n] = __builtin_amdgcn_mfma_f32_16x16x32_bf16(al[m], bh[n], acc[m][n], 0, 0, 0);
      }
  }

  // epilogue: C row = (lane>>4)*4 + reg (within 16), col = lane&15
  const int rq = lane >> 4;
  const int cl = lane & 15;
#pragma unroll
  for (int n = 0; n < 4; ++n) {
    const int gn = bn0 + wc * 64 + n * 16 + cl;
    const float bv = bias[gn];
    if (MODE == 0) {
      const int which = gn >> 10;
      const int hh = (gn >> 6) & 15;
      const int d = gn & 63;
      float* dst = (which == 0) ? C0 : (which == 1) ? C1 : C2;
#pragma unroll
      for (int m = 0; m < 4; ++m)
#pragma unroll
        for (int j = 0; j < 4; ++j) {
          const int gm = bm0 + wr * 64 + m * 16 + rq * 4 + j;
          const int b = gm >> 13;
          const int s = gm & 8191;
          dst[((size_t)(b * NH + hh) * S_LEN + s) * DH + d] = acc[m][n][j] + bv;
        }
    } else {
#pragma unroll
      for (int m = 0; m < 4; ++m)
#pragma unroll
        for (int j = 0; j < 4; ++j) {
          const int gm = bm0 + wr * 64 + m * 16 + rq * 4 + j;
          C0[(size_t)gm * N + gn] = acc[m][n][j] + bv;
        }
    }
  }
}

// ---------------------------------------------------------------------------
// FP32 attention over one 64-query chunk of one (b, h, group).
// Output written as bf16 hi/lo split, scattered into (B,S,E) for GEMM2.
// ---------------------------------------------------------------------------
__global__ __launch_bounds__(256) void attn_kernel(
    const float* __restrict__ q, const float* __restrict__ k,
    const float* __restrict__ v, const int* __restrict__ idx,
    unsigned short* __restrict__ out_hi, unsigned short* __restrict__ out_lo) {
  __shared__ float Qs[64][68];
  __shared__ float KP[64][68];
  __shared__ float Vs[64][68];

  const int bid = blockIdx.x;
  const int bh = bid >> 7;
  const int c = bid & 127;
  const int b = bh >> 4;
  const int h = bh & 15;
  int idx_base, qoff, g;
  if (c < 16) { idx_base = 0; qoff = c * 64; g = 1024; }
  else {
    int t = c - 16;
    idx_base = 1024 + (t >> 3) * 512;
    qoff = (t & 7) * 64;
    g = 512;
  }

  const size_t bh_off = (size_t)(b * NH + h) * S_LEN * DH;
  const float* qb = q + bh_off;
  const float* kb = k + bh_off;
  const float* vb = v + bh_off;

  const int tid = threadIdx.x;
  const int tx = tid & 15;
  const int ty = tid >> 4;
  const int sr = tid >> 2;
  const int scb = (tid & 3) * 16;

  {
    int grow = idx[idx_base + qoff + sr];
    const float* src = qb + (size_t)grow * DH + scb;
#pragma unroll
    for (int u = 0; u < 4; ++u) {
      floatx4 val = *(const floatx4*)(src + u * 4);
#pragma unroll
      for (int ii = 0; ii < 4; ++ii) Qs[scb + u * 4 + ii][sr] = val[ii] * 0.125f;
    }
  }

  float m[4], l[4], o[4][4];
#pragma unroll
  for (int i = 0; i < 4; ++i) {
    m[i] = -1e30f; l[i] = 0.f;
#pragma unroll
    for (int j = 0; j < 4; ++j) o[i][j] = 0.f;
  }

  const int ntiles = g >> 6;
  for (int kt = 0; kt < ntiles; ++kt) {
    int grow = idx[idx_base + kt * 64 + sr];
    const float* ksrc = kb + (size_t)grow * DH + scb;
    const float* vsrc = vb + (size_t)grow * DH + scb;
    __syncthreads();
#pragma unroll
    for (int u = 0; u < 4; ++u) {
      floatx4 kv = *(const floatx4*)(ksrc + u * 4);
      floatx4 vv = *(const floatx4*)(vsrc + u * 4);
#pragma unroll
      for (int ii = 0; ii < 4; ++ii) KP[scb + u * 4 + ii][sr] = kv[ii];
      *(floatx4*)&Vs[sr][scb + u * 4] = vv;
    }
    __syncthreads();

    float sc_[4][4];
#pragma unroll
    for (int i = 0; i < 4; ++i)
#pragma unroll
      for (int j = 0; j < 4; ++j) sc_[i][j] = 0.f;
#pragma unroll 8
    for (int d = 0; d < 64; ++d) {
      floatx4 qv = *(const floatx4*)&Qs[d][ty * 4];
      floatx4 kv = *(const floatx4*)&KP[d][tx * 4];
#pragma unroll
      for (int i = 0; i < 4; ++i)
#pragma unroll
        for (int j = 0; j < 4; ++j) sc_[i][j] += qv[i] * kv[j];
    }

#pragma unroll
    for (int i = 0; i < 4; ++i) {
      float mx = fmaxf(fmaxf(sc_[i][0], sc_[i][1]), fmaxf(sc_[i][2], sc_[i][3]));
#pragma unroll
      for (int w = 1; w < 16; w <<= 1) mx = fmaxf(mx, __shfl_xor(mx, w, 16));
      float mn = fmaxf(m[i], mx);
      float rescale = __expf(m[i] - mn);
      float su = 0.f;
#pragma unroll
      for (int j = 0; j < 4; ++j) { sc_[i][j] = __expf(sc_[i][j] - mn); su += sc_[i][j]; }
#pragma unroll
      for (int w = 1; w < 16; w <<= 1) su += __shfl_xor(su, w, 16);
      l[i] = l[i] * rescale + su;
      m[i] = mn;
#pragma unroll
      for (int j = 0; j < 4; ++j) o[i][j] *= rescale;
    }
    __syncthreads();

#pragma unroll
    for (int i = 0; i < 4; ++i)
#pragma unroll
      for (int j = 0; j < 4; ++j)
        KP[tx * 4 + j][ty * 4 + i] = sc_[i][j];
    __syncthreads();

#pragma unroll 8
    for (int kc = 0; kc < 64; ++kc) {
      floatx4 pv = *(const floatx4*)&KP[kc][ty * 4];
      floatx4 vv = *(const floatx4*)&Vs[kc][tx * 4];
#pragma unroll
      for (int i = 0; i < 4; ++i)
#pragma unroll
        for (int j = 0; j < 4; ++j) o[i][j] += pv[i] * vv[j];
    }
  }

#pragma unroll
  for (int i = 0; i < 4; ++i) {
    float inv = 1.f / l[i];
    int grow = idx[idx_base + qoff + ty * 4 + i];
    u16x4 hv, lv;
#pragma unroll
    for (int j = 0; j < 4; ++j) {
      float val = o[i][j] * inv;
      unsigned short hb = f2bf(val);
      hv[j] = hb;
      lv[j] = f2bf(val - bf2f(hb));
    }
    size_t base = ((size_t)b * S_LEN + grow) * EE + h * DH + tx * 4;
    *(u16x4*)(out_hi + base) = hv;
    *(u16x4*)(out_lo + base) = lv;
  }
}

// ---------------------------------------------------------------------------
extern "C" void kernel_launch(void* const* d_in, const int* in_sizes, int n_in,
                              void* d_out, int out_size, void* d_ws, size_t ws_size,
                              hipStream_t stream) {
  const float* x     = (const float*)d_in[0];
  const float* w_qkv = (const float*)d_in[1];
  const float* b_qkv = (const float*)d_in[2];
  const float* w_out = (const float*)d_in[3];
  const float* b_out = (const float*)d_in[4];
  float* outp = (float*)d_out;
  float* ws = (float*)d_ws;

  const size_t per = (size_t)BB * S_LEN * EE;  // 16,777,216
  const size_t nwq = (size_t)3 * EE * EE;      // 3,145,728
  const size_t nwo = (size_t)EE * EE;          // 1,048,576

  float* kbuf = ws;
  float* vbuf = ws + per;
  unsigned short* xhi = (unsigned short*)(ws + 2 * per);
  unsigned short* xlo = xhi + per;   // region reused as attn hi/lo after GEMM1
  unsigned short* wqh = xlo + per;
  unsigned short* wql = wqh + nwq;
  unsigned short* woh = wql + nwq;
  unsigned short* wol = woh + nwo;
  int* idx = (int*)(wol + nwo);
  float* qbuf = outp;  // q lives in d_out until GEMM2 overwrites it

  build_idx_kernel<<<4, 256, 0, stream>>>(idx);
  split_kernel<<<(int)(per / 2048), 256, 0, stream>>>(x, xhi, xlo, (int)per);
  split_kernel<<<(int)(nwq / 2048), 256, 0, stream>>>(w_qkv, wqh, wql, (int)nwq);
  split_kernel<<<(int)(nwo / 2048), 256, 0, stream>>>(w_out, woh, wol, (int)nwo);

  mgemm_kernel<0><<<dim3(128, 24), 256, 0, stream>>>(
      xhi, xlo, wqh, wql, b_qkv, qbuf, kbuf, vbuf, 3 * EE, EE);
  attn_kernel<<<4096, 256, 0, stream>>>(qbuf, kbuf, vbuf, idx, xhi, xlo);
  mgemm_kernel<1><<<dim3(128, 8), 256, 0, stream>>>(
      xhi, xlo, woh, wol, b_out, outp, nullptr, nullptr, EE, EE);
}

// Round 3
// 942.585 us; speedup vs baseline: 2.4232x; 1.2387x over previous
//
#include <hip/hip_runtime.h>
#include <hip/hip_bf16.h>
#include <math.h>

#define S_LEN 8192
#define NH 16
#define DH 64
#define BB 2
#define EE 1024

typedef float floatx4 __attribute__((ext_vector_type(4)));
typedef float f32x4 __attribute__((ext_vector_type(4)));
typedef short bf16x8 __attribute__((ext_vector_type(8)));
typedef int i32x4 __attribute__((ext_vector_type(4)));
typedef unsigned short u16x4 __attribute__((ext_vector_type(4)));

__device__ inline unsigned short f2bf(float x) {
  unsigned int u = __builtin_bit_cast(unsigned int, x);
  u += 0x7FFFu + ((u >> 16) & 1u);
  return (unsigned short)(u >> 16);
}
__device__ inline float bf2f(unsigned short h) {
  return __builtin_bit_cast(float, (unsigned int)h << 16);
}

__device__ inline void async_copy16(void* lds, const void* g) {
  __builtin_amdgcn_global_load_lds(
      (const __attribute__((address_space(1))) void*)g,
      (__attribute__((address_space(3))) void*)lds, 16, 0, 0);
}

// ---------------------------------------------------------------------------
// Hilbert curve d-index (matches reference _xy2d).
// ---------------------------------------------------------------------------
__device__ inline int hilbert_xy2d(int n, int x, int y) {
  int d = 0;
  for (int s = n >> 1; s > 0; s >>= 1) {
    int rx = (x & s) ? 1 : 0;
    int ry = (y & s) ? 1 : 0;
    d += s * s * ((3 * rx) ^ ry);
    if (ry == 0) {
      if (rx == 1) { x = s - 1 - x; y = s - 1 - y; }
      int t = x; x = y; y = t;
    }
  }
  return d;
}

__global__ void build_idx_kernel(int* __restrict__ idx) {
  __shared__ int order[4096];
  __shared__ int perm[4096];
  __shared__ int cnts[256];
  const int seg = blockIdx.x;
  const int posA[4] = {0, 1024, 2048, 4096};
  const int LA[4]   = {1024, 1024, 2048, 4096};
  const int pos = posA[seg];
  const int L = LA[seg];
  const int lr = seg;  // log2(rate)
  const int side  = (L <= 1024) ? 32 : 64;
  const int lside = (L <= 1024) ? 5 : 6;
  const int cells = side * side;
  const int tid = threadIdx.x;

  for (int c = tid; c < cells; c += 256) {
    int x = c & (side - 1);
    int y = c >> lside;
    order[hilbert_xy2d(side, x, y)] = c;
  }
  __syncthreads();

  if (L == cells) {
    for (int t = tid; t < L; t += 256) perm[t] = order[t];
  } else {
    const int per = cells >> 8;  // 16
    const int base = tid * per;
    int cnt = 0;
    for (int u = 0; u < per; ++u) cnt += (order[base + u] < L) ? 1 : 0;
    cnts[tid] = cnt;
    __syncthreads();
    if (tid == 0) {
      int s = 0;
      for (int i = 0; i < 256; ++i) { int c0 = cnts[i]; cnts[i] = s; s += c0; }
    }
    __syncthreads();
    int r = cnts[tid];
    for (int u = 0; u < per; ++u) {
      int o = order[base + u];
      if (o < L) perm[r++] = o;
    }
  }
  __syncthreads();

  const int g = L >> lr;
  const int rm = (1 << lr) - 1;
  for (int t = tid; t < L; t += 256) {
    int j = t & rm;
    int i = t >> lr;
    idx[pos + j * g + i] = pos + perm[t];
  }
}

// ---------------------------------------------------------------------------
// Split fp32 -> bf16 hi + bf16 lo (residual). 8 elems/thread.
// ---------------------------------------------------------------------------
__global__ __launch_bounds__(256) void split_kernel(
    const float* __restrict__ in, unsigned short* __restrict__ hi,
    unsigned short* __restrict__ lo, int n) {
  int base = (blockIdx.x * 256 + threadIdx.x) * 8;
  if (base >= n) return;
  floatx4 v0 = *(const floatx4*)(in + base);
  floatx4 v1 = *(const floatx4*)(in + base + 4);
  u16x4 h0, h1, l0, l1;
#pragma unroll
  for (int i = 0; i < 4; ++i) {
    unsigned short h = f2bf(v0[i]);
    h0[i] = h; l0[i] = f2bf(v0[i] - bf2f(h));
    unsigned short h2 = f2bf(v1[i]);
    h1[i] = h2; l1[i] = f2bf(v1[i] - bf2f(h2));
  }
  *(u16x4*)(hi + base) = h0;
  *(u16x4*)(hi + base + 4) = h1;
  *(u16x4*)(lo + base) = l0;
  *(u16x4*)(lo + base + 4) = l1;
}

// ---------------------------------------------------------------------------
// bf16x3 split MFMA GEMM: C = A(MxK) @ B(NxK)^T + bias, fp32-accurate.
// 128x128 tile, BK=32, 256 threads (4 waves, 2x2), fragment-linear LDS.
// MODE 0: split hi/lo scatter into q/k/v (B,H,S,D); q pre-scaled by 0.125.
// MODE 1: plain row-major fp32 C.
// ---------------------------------------------------------------------------
template<int MODE>
__global__ __launch_bounds__(256) void mgemm_kernel(
    const unsigned short* __restrict__ Ahi, const unsigned short* __restrict__ Alo,
    const unsigned short* __restrict__ Bhi, const unsigned short* __restrict__ Blo,
    const float* __restrict__ bias, float* __restrict__ Cf,
    unsigned short* __restrict__ q_h, unsigned short* __restrict__ q_l,
    unsigned short* __restrict__ k_h, unsigned short* __restrict__ k_l,
    unsigned short* __restrict__ v_h, unsigned short* __restrict__ v_l,
    int N, int K) {
  __shared__ short lds[16384];
  const int tid = threadIdx.x;
  const int lane = tid & 63;
  const int w = tid >> 6;
  const int wr = w >> 1, wc = w & 1;
  const int bm0 = blockIdx.x * 128;
  const int bn0 = blockIdx.y * 128;

  const unsigned short* srcbase = (w == 0) ? Ahi : (w == 1) ? Alo
                                 : (w == 2) ? Bhi : Blo;
  const int row0 = (w < 2) ? bm0 : bn0;
  const unsigned short* sp =
      srcbase + (size_t)(row0 + (lane & 15)) * K + (lane >> 4) * 8;
  short* ldst = &lds[w * 4096];

  f32x4 acc[4][4];
#pragma unroll
  for (int m = 0; m < 4; ++m)
#pragma unroll
    for (int n = 0; n < 4; ++n) acc[m][n] = (f32x4)0.f;

  for (int k0 = 0; k0 < K; k0 += 32) {
    __syncthreads();
#pragma unroll
    for (int g = 0; g < 8; ++g)
      async_copy16(ldst + g * 512, sp + (size_t)g * 16 * K + k0);
    __syncthreads();

    bf16x8 ah[4], al[4], bh[4], bl[4];
#pragma unroll
    for (int m = 0; m < 4; ++m) {
      ah[m] = *(const bf16x8*)&lds[0 * 4096 + (wr * 4 + m) * 512 + lane * 8];
      al[m] = *(const bf16x8*)&lds[1 * 4096 + (wr * 4 + m) * 512 + lane * 8];
    }
#pragma unroll
    for (int n = 0; n < 4; ++n) {
      bh[n] = *(const bf16x8*)&lds[2 * 4096 + (wc * 4 + n) * 512 + lane * 8];
      bl[n] = *(const bf16x8*)&lds[3 * 4096 + (wc * 4 + n) * 512 + lane * 8];
    }
#pragma unroll
    for (int m = 0; m < 4; ++m)
#pragma unroll
      for (int n = 0; n < 4; ++n) {
        acc[m][n] = __builtin_amdgcn_mfma_f32_16x16x32_bf16(ah[m], bh[n], acc[m][n], 0, 0, 0);
        acc[m][n] = __builtin_amdgcn_mfma_f32_16x16x32_bf16(ah[m], bl[n], acc[m][n], 0, 0, 0);
        acc[m][n] = __builtin_amdgcn_mfma_f32_16x16x32_bf16(al[m], bh[n], acc[m][n], 0, 0, 0);
      }
  }

  const int rq = lane >> 4;
  const int cl = lane & 15;
#pragma unroll
  for (int n = 0; n < 4; ++n) {
    const int gn = bn0 + wc * 64 + n * 16 + cl;
    const float bv = bias[gn];
    if (MODE == 0) {
      const int which = gn >> 10;
      const int hh = (gn >> 6) & 15;
      const int d = gn & 63;
      const float scale = (which == 0) ? 0.125f : 1.0f;
      unsigned short* dsth = (which == 0) ? q_h : (which == 1) ? k_h : v_h;
      unsigned short* dstl = (which == 0) ? q_l : (which == 1) ? k_l : v_l;
#pragma unroll
      for (int m = 0; m < 4; ++m)
#pragma unroll
        for (int j = 0; j < 4; ++j) {
          const int gm = bm0 + wr * 64 + m * 16 + rq * 4 + j;
          const int b = gm >> 13;
          const int s = gm & 8191;
          float val = (acc[m][n][j] + bv) * scale;
          unsigned int u = __builtin_bit_cast(unsigned int, val);
          float lf = val - __builtin_bit_cast(float, u & 0xFFFF0000u);
          size_t off = ((size_t)(b * NH + hh) * S_LEN + s) * DH + d;
          dsth[off] = (unsigned short)(u >> 16);
          dstl[off] = (unsigned short)(__builtin_bit_cast(unsigned int, lf) >> 16);
        }
    } else {
#pragma unroll
      for (int m = 0; m < 4; ++m)
#pragma unroll
        for (int j = 0; j < 4; ++j) {
          const int gm = bm0 + wr * 64 + m * 16 + rq * 4 + j;
          Cf[(size_t)gm * N + gn] = acc[m][n][j] + bv;
        }
    }
  }
}

// ---------------------------------------------------------------------------
// MFMA flash attention, split bf16 (hh+hl+lh), swapped QK^T.
// Block = (b, h, group, 256-q chunk); 4 waves x 64 q-rows; KV tiles of 64.
// K staged via pre-swizzled-source global_load_lds; V transposed at staging.
// P repacked C-layout -> B-frag purely with shuffles (no LDS round trip).
// ---------------------------------------------------------------------------
__global__ __launch_bounds__(256, 2) void mattn_kernel(
    const unsigned short* __restrict__ qhi, const unsigned short* __restrict__ qlo,
    const unsigned short* __restrict__ khi, const unsigned short* __restrict__ klo,
    const unsigned short* __restrict__ vhi, const unsigned short* __restrict__ vlo,
    const int* __restrict__ idx,
    unsigned short* __restrict__ ohi, unsigned short* __restrict__ olo) {
  // LDS: Khi [0,8K) Klo [8K,16K) VhiT [16K,24K) VloT [24K,32K) idxg [32K,36K)
  // K/V rows 128B, XOR swizzle byte ^= (row&7)<<4
  __shared__ __align__(16) char smem[36864];
  int* idxg = (int*)(smem + 32768);

  const int tid = threadIdx.x;
  const int lane = tid & 63;
  const int w = tid >> 6;
  const int g = lane >> 4;
  const int q = lane & 15;

  const int c = blockIdx.x;
  const int bh = blockIdx.y;
  const int bb = bh >> 4;
  const int h = bh & 15;
  int gbase, glen, q0;
  if (c < 4) { gbase = 0; glen = 1024; q0 = c * 256; }
  else { int t = c - 4; gbase = 1024 + (t >> 1) * 512; glen = 512; q0 = (t & 1) * 256; }

  for (int i = tid; i < glen; i += 256) idxg[i] = idx[gbase + i];
  __syncthreads();

  const size_t bhoff = (size_t)(bb * NH + h) * S_LEN * DH;
  const unsigned short* qhb = qhi + bhoff;
  const unsigned short* qlb = qlo + bhoff;
  const unsigned short* khb = khi + bhoff;
  const unsigned short* klb = klo + bhoff;
  const unsigned short* vhb = vhi + bhoff;
  const unsigned short* vlb = vlo + bhoff;

  int qrow[4];
#pragma unroll
  for (int qt = 0; qt < 4; ++qt) qrow[qt] = idxg[q0 + w * 64 + qt * 16 + q];

  f32x4 oacc[4][4];
#pragma unroll
  for (int dt = 0; dt < 4; ++dt)
#pragma unroll
    for (int qt = 0; qt < 4; ++qt) oacc[dt][qt] = (f32x4)0.f;
  float mq[4] = {-1e30f, -1e30f, -1e30f, -1e30f};
  float lq[4] = {0.f, 0.f, 0.f, 0.f};

  const int nt = glen >> 6;
  for (int kt_ = 0; kt_ < nt; ++kt_) {
    const int kt0 = kt_ * 64;
    __syncthreads();  // previous tile's LDS reads done

    // --- stage K: 4 global_load_lds per wave, source pre-swizzled ---
#pragma unroll
    for (int ii = 0; ii < 4; ++ii) {
      int i = w * 4 + ii;
      const unsigned short* ka = (i < 8) ? khb : klb;
      int ldsb = (i < 8) ? 0 : 8192;
      int g8 = i & 7;
      int r = g8 * 8 + (lane >> 3);
      int bsw = (lane & 7) ^ (r & 7);
      async_copy16(smem + ldsb + g8 * 1024,
                   ka + (size_t)idxg[kt0 + r] * DH + bsw * 8);
    }
    // --- stage V^T: reg load, pack k-pairs to u32, swizzled ds_write ---
    {
      const unsigned short* va = (tid < 128) ? vhb : vlb;
      char* vbase = smem + 16384 + ((tid < 128) ? 0 : 8192);
      int rem = tid & 127;
      int p = rem & 31;
      int dh = (rem >> 5) * 16;
      int r0 = idxg[kt0 + 2 * p], r1 = idxg[kt0 + 2 * p + 1];
      bf16x8 A0 = *(const bf16x8*)(va + (size_t)r0 * DH + dh);
      bf16x8 A1 = *(const bf16x8*)(va + (size_t)r0 * DH + dh + 8);
      bf16x8 B0 = *(const bf16x8*)(va + (size_t)r1 * DH + dh);
      bf16x8 B1 = *(const bf16x8*)(va + (size_t)r1 * DH + dh + 8);
#pragma unroll
      for (int u = 0; u < 16; ++u) {
        unsigned short a = (unsigned short)((u < 8) ? A0[u] : A1[u - 8]);
        unsigned short b2 = (unsigned short)((u < 8) ? B0[u] : B1[u - 8]);
        unsigned int w32 = (unsigned int)a | ((unsigned int)b2 << 16);
        int d = dh + u;
        int byte_ = (d * 128 + p * 4) ^ ((d & 7) << 4);
        *(unsigned int*)(vbase + byte_) = w32;
      }
    }
    __syncthreads();  // staging visible

    // --- S^T = mfma(K, Q): lane holds q=lane&15, k = kt*16 + 4g + j ---
    f32x4 sacc[4][4];
#pragma unroll
    for (int qt = 0; qt < 4; ++qt)
#pragma unroll
      for (int kt = 0; kt < 4; ++kt) sacc[qt][kt] = (f32x4)0.f;
#pragma unroll
    for (int dc = 0; dc < 2; ++dc) {
      bf16x8 kh[4], kl[4];
#pragma unroll
      for (int kt = 0; kt < 4; ++kt) {
        int r = q + 16 * kt;
        int byte_ = (r * 128 + g * 16 + dc * 64) ^ ((r & 7) << 4);
        kh[kt] = *(const bf16x8*)(smem + byte_);
        kl[kt] = *(const bf16x8*)(smem + 8192 + byte_);
      }
#pragma unroll
      for (int qt = 0; qt < 4; ++qt) {
        bf16x8 qhf = *(const bf16x8*)(qhb + (size_t)qrow[qt] * DH + dc * 32 + g * 8);
        bf16x8 qlf = *(const bf16x8*)(qlb + (size_t)qrow[qt] * DH + dc * 32 + g * 8);
#pragma unroll
        for (int kt = 0; kt < 4; ++kt) {
          sacc[qt][kt] = __builtin_amdgcn_mfma_f32_16x16x32_bf16(kh[kt], qhf, sacc[qt][kt], 0, 0, 0);
          sacc[qt][kt] = __builtin_amdgcn_mfma_f32_16x16x32_bf16(kh[kt], qlf, sacc[qt][kt], 0, 0, 0);
          sacc[qt][kt] = __builtin_amdgcn_mfma_f32_16x16x32_bf16(kl[kt], qhf, sacc[qt][kt], 0, 0, 0);
        }
      }
    }

    // --- online softmax + truncation hi/lo pack + shuffle repack ---
    i32x4 pfh[4][2], pfl[4][2];
#pragma unroll
    for (int qt = 0; qt < 4; ++qt) {
      float mold = mq[qt];
      float tm = -1e30f;
#pragma unroll
      for (int kt = 0; kt < 4; ++kt)
#pragma unroll
        for (int j = 0; j < 4; ++j) tm = fmaxf(tm, sacc[qt][kt][j]);
      tm = fmaxf(tm, __shfl_xor(tm, 16));
      tm = fmaxf(tm, __shfl_xor(tm, 32));
      float mn = fmaxf(mold, tm);
      float su = 0.f;
#pragma unroll
      for (int kt = 0; kt < 4; ++kt)
#pragma unroll
        for (int j = 0; j < 4; ++j) {
          float pv = __expf(sacc[qt][kt][j] - mn);
          sacc[qt][kt][j] = pv;
          su += pv;
        }
      su += __shfl_xor(su, 16);
      su += __shfl_xor(su, 32);
      float rs = __expf(mold - mn);
      lq[qt] = lq[qt] * rs + su;
      mq[qt] = mn;
      if (__any(mn > mold)) {
#pragma unroll
        for (int dt = 0; dt < 4; ++dt) oacc[dt][qt] *= rs;
      }
      unsigned int eh[4][2], el[4][2];
#pragma unroll
      for (int kt = 0; kt < 4; ++kt)
#pragma unroll
        for (int p = 0; p < 2; ++p) {
          float a = sacc[qt][kt][2 * p], b2 = sacc[qt][kt][2 * p + 1];
          unsigned int ua = __builtin_bit_cast(unsigned int, a);
          unsigned int ub = __builtin_bit_cast(unsigned int, b2);
          eh[kt][p] = (ua >> 16) | (ub & 0xFFFF0000u);
          float la = a - __builtin_bit_cast(float, ua & 0xFFFF0000u);
          float lb = b2 - __builtin_bit_cast(float, ub & 0xFFFF0000u);
          el[kt][p] = (__builtin_bit_cast(unsigned int, la) >> 16) |
                      (__builtin_bit_cast(unsigned int, lb) & 0xFFFF0000u);
        }
      // C-layout -> B-frag: dest k' = 8g + j; src kt = 2kc + (g>>1),
      // src lane = q + 32*(g&1) + 16*(t>>1), pair p = t&1.
#pragma unroll
      for (int kc = 0; kc < 2; ++kc) {
        i32x4 fh, fl;
#pragma unroll
        for (int t = 0; t < 4; ++t) {
          int src = q + 32 * (g & 1) + 16 * (t >> 1);
          int ah = __shfl((int)eh[2 * kc][t & 1], src);
          int bh2 = __shfl((int)eh[2 * kc + 1][t & 1], src);
          int al = __shfl((int)el[2 * kc][t & 1], src);
          int bl2 = __shfl((int)el[2 * kc + 1][t & 1], src);
          fh[t] = (g >> 1) ? bh2 : ah;
          fl[t] = (g >> 1) ? bl2 : al;
        }
        pfh[qt][kc] = fh;
        pfl[qt][kc] = fl;
      }
    }

    // --- O^T += mfma(V^T, P) ---
#pragma unroll
    for (int kc = 0; kc < 2; ++kc)
#pragma unroll
      for (int dt = 0; dt < 4; ++dt) {
        int r = q + 16 * dt;
        int byte_ = (r * 128 + g * 16 + kc * 64) ^ ((r & 7) << 4);
        bf16x8 vh = *(const bf16x8*)(smem + 16384 + byte_);
        bf16x8 vl = *(const bf16x8*)(smem + 24576 + byte_);
#pragma unroll
        for (int qt = 0; qt < 4; ++qt) {
          bf16x8 ph = __builtin_bit_cast(bf16x8, pfh[qt][kc]);
          bf16x8 pl = __builtin_bit_cast(bf16x8, pfl[qt][kc]);
          oacc[dt][qt] = __builtin_amdgcn_mfma_f32_16x16x32_bf16(vh, ph, oacc[dt][qt], 0, 0, 0);
          oacc[dt][qt] = __builtin_amdgcn_mfma_f32_16x16x32_bf16(vh, pl, oacc[dt][qt], 0, 0, 0);
          oacc[dt][qt] = __builtin_amdgcn_mfma_f32_16x16x32_bf16(vl, ph, oacc[dt][qt], 0, 0, 0);
        }
      }
  }

  // --- epilogue: normalize, split hi/lo, scatter to (B,S,E) ---
#pragma unroll
  for (int qt = 0; qt < 4; ++qt) {
    float inv = 1.f / lq[qt];
    size_t obase = ((size_t)bb * S_LEN + qrow[qt]) * EE + h * DH;
#pragma unroll
    for (int dt = 0; dt < 4; ++dt) {
      u16x4 hv, lv;
#pragma unroll
      for (int j = 0; j < 4; ++j) {
        float val = oacc[dt][qt][j] * inv;
        unsigned int u = __builtin_bit_cast(unsigned int, val);
        hv[j] = (unsigned short)(u >> 16);
        float lf = val - __builtin_bit_cast(float, u & 0xFFFF0000u);
        lv[j] = (unsigned short)(__builtin_bit_cast(unsigned int, lf) >> 16);
      }
      *(u16x4*)(ohi + obase + dt * 16 + g * 4) = hv;
      *(u16x4*)(olo + obase + dt * 16 + g * 4) = lv;
    }
  }
}

// ---------------------------------------------------------------------------
extern "C" void kernel_launch(void* const* d_in, const int* in_sizes, int n_in,
                              void* d_out, int out_size, void* d_ws, size_t ws_size,
                              hipStream_t stream) {
  const float* x     = (const float*)d_in[0];
  const float* w_qkv = (const float*)d_in[1];
  const float* b_qkv = (const float*)d_in[2];
  const float* w_out = (const float*)d_in[3];
  const float* b_out = (const float*)d_in[4];
  float* outp = (float*)d_out;

  const size_t per = (size_t)BB * S_LEN * EE;  // 16,777,216
  const size_t nwq = (size_t)3 * EE * EE;
  const size_t nwo = (size_t)EE * EE;

  unsigned short* khi = (unsigned short*)d_ws;
  unsigned short* klo = khi + per;
  unsigned short* vhi = klo + per;
  unsigned short* vlo = vhi + per;
  unsigned short* xhi = vlo + per;
  unsigned short* xlo = xhi + per;
  unsigned short* wqh = xlo + per;
  unsigned short* wql = wqh + nwq;
  unsigned short* woh = wql + nwq;
  unsigned short* wol = woh + nwo;
  int* idx = (int*)(wol + nwo);

  unsigned short* qhi = (unsigned short*)d_out;  // q lives in d_out until GEMM2
  unsigned short* qlo = qhi + per;
  unsigned short* ahi = xhi;  // x dead after GEMM1; reuse for attn output
  unsigned short* alo = xlo;

  build_idx_kernel<<<4, 256, 0, stream>>>(idx);
  split_kernel<<<(int)(per / 2048), 256, 0, stream>>>(x, xhi, xlo, (int)per);
  split_kernel<<<(int)(nwq / 2048), 256, 0, stream>>>(w_qkv, wqh, wql, (int)nwq);
  split_kernel<<<(int)(nwo / 2048), 256, 0, stream>>>(w_out, woh, wol, (int)nwo);

  mgemm_kernel<0><<<dim3(128, 24), 256, 0, stream>>>(
      xhi, xlo, wqh, wql, b_qkv, nullptr,
      qhi, qlo, khi, klo, vhi, vlo, 3 * EE, EE);
  mattn_kernel<<<dim3(32, 32), 256, 0, stream>>>(
      qhi, qlo, khi, klo, vhi, vlo, idx, ahi, alo);
  mgemm_kernel<1><<<dim3(128, 8), 256, 0, stream>>>(
      ahi, alo, woh, wol, b_out, outp,
      nullptr, nullptr, nullptr, nullptr, nullptr, nullptr, EE, EE);
}

// Round 4
// 938.235 us; speedup vs baseline: 2.4344x; 1.0046x over previous
//
#include <hip/hip_runtime.h>
#include <hip/hip_bf16.h>
#include <math.h>

#define S_LEN 8192
#define NH 16
#define DH 64
#define BB 2
#define EE 1024

typedef float floatx4 __attribute__((ext_vector_type(4)));
typedef float f32x4 __attribute__((ext_vector_type(4)));
typedef short bf16x8 __attribute__((ext_vector_type(8)));
typedef int i32x4 __attribute__((ext_vector_type(4)));
typedef unsigned short u16x4 __attribute__((ext_vector_type(4)));

__device__ inline unsigned short f2bf(float x) {
  unsigned int u = __builtin_bit_cast(unsigned int, x);
  u += 0x7FFFu + ((u >> 16) & 1u);
  return (unsigned short)(u >> 16);
}
__device__ inline float bf2f(unsigned short h) {
  return __builtin_bit_cast(float, (unsigned int)h << 16);
}

__device__ inline void async_copy16(void* lds, const void* g) {
  __builtin_amdgcn_global_load_lds(
      (const __attribute__((address_space(1))) void*)g,
      (__attribute__((address_space(3))) void*)lds, 16, 0, 0);
}

// ---------------------------------------------------------------------------
// Hilbert curve d-index (matches reference _xy2d).
// ---------------------------------------------------------------------------
__device__ inline int hilbert_xy2d(int n, int x, int y) {
  int d = 0;
  for (int s = n >> 1; s > 0; s >>= 1) {
    int rx = (x & s) ? 1 : 0;
    int ry = (y & s) ? 1 : 0;
    d += s * s * ((3 * rx) ^ ry);
    if (ry == 0) {
      if (rx == 1) { x = s - 1 - x; y = s - 1 - y; }
      int t = x; x = y; y = t;
    }
  }
  return d;
}

__global__ void build_idx_kernel(int* __restrict__ idx) {
  __shared__ int order[4096];
  __shared__ int perm[4096];
  __shared__ int cnts[256];
  const int seg = blockIdx.x;
  const int posA[4] = {0, 1024, 2048, 4096};
  const int LA[4]   = {1024, 1024, 2048, 4096};
  const int pos = posA[seg];
  const int L = LA[seg];
  const int lr = seg;  // log2(rate)
  const int side  = (L <= 1024) ? 32 : 64;
  const int lside = (L <= 1024) ? 5 : 6;
  const int cells = side * side;
  const int tid = threadIdx.x;

  for (int c = tid; c < cells; c += 256) {
    int x = c & (side - 1);
    int y = c >> lside;
    order[hilbert_xy2d(side, x, y)] = c;
  }
  __syncthreads();

  if (L == cells) {
    for (int t = tid; t < L; t += 256) perm[t] = order[t];
  } else {
    const int per = cells >> 8;  // 16
    const int base = tid * per;
    int cnt = 0;
    for (int u = 0; u < per; ++u) cnt += (order[base + u] < L) ? 1 : 0;
    cnts[tid] = cnt;
    __syncthreads();
    if (tid == 0) {
      int s = 0;
      for (int i = 0; i < 256; ++i) { int c0 = cnts[i]; cnts[i] = s; s += c0; }
    }
    __syncthreads();
    int r = cnts[tid];
    for (int u = 0; u < per; ++u) {
      int o = order[base + u];
      if (o < L) perm[r++] = o;
    }
  }
  __syncthreads();

  const int g = L >> lr;
  const int rm = (1 << lr) - 1;
  for (int t = tid; t < L; t += 256) {
    int j = t & rm;
    int i = t >> lr;
    idx[pos + j * g + i] = pos + perm[t];
  }
}

// ---------------------------------------------------------------------------
// Split fp32 -> bf16 hi + bf16 lo (residual). 8 elems/thread.
// ---------------------------------------------------------------------------
__global__ __launch_bounds__(256) void split_kernel(
    const float* __restrict__ in, unsigned short* __restrict__ hi,
    unsigned short* __restrict__ lo, int n) {
  int base = (blockIdx.x * 256 + threadIdx.x) * 8;
  if (base >= n) return;
  floatx4 v0 = *(const floatx4*)(in + base);
  floatx4 v1 = *(const floatx4*)(in + base + 4);
  u16x4 h0, h1, l0, l1;
#pragma unroll
  for (int i = 0; i < 4; ++i) {
    unsigned short h = f2bf(v0[i]);
    h0[i] = h; l0[i] = f2bf(v0[i] - bf2f(h));
    unsigned short h2 = f2bf(v1[i]);
    h1[i] = h2; l1[i] = f2bf(v1[i] - bf2f(h2));
  }
  *(u16x4*)(hi + base) = h0;
  *(u16x4*)(hi + base + 4) = h1;
  *(u16x4*)(lo + base) = l0;
  *(u16x4*)(lo + base + 4) = l1;
}

// ---------------------------------------------------------------------------
// bf16x3 split MFMA GEMM: C = A(MxK) @ B(NxK)^T + bias, fp32-accurate.
// 128x128 tile, BK=32, 256 threads (4 waves, 2x2), fragment-linear LDS,
// DOUBLE-BUFFERED with 2-phase prefetch: next K-tile's global_load_lds are
// issued before the current tile's ds_read+MFMA (T3 minimum recipe).
// MODE 0: split hi/lo scatter into q/k/v (B,H,S,D); q pre-scaled by 0.125.
// MODE 1: plain row-major fp32 C.
// ---------------------------------------------------------------------------
template<int MODE>
__global__ __launch_bounds__(256) void mgemm_kernel(
    const unsigned short* __restrict__ Ahi, const unsigned short* __restrict__ Alo,
    const unsigned short* __restrict__ Bhi, const unsigned short* __restrict__ Blo,
    const float* __restrict__ bias, float* __restrict__ Cf,
    unsigned short* __restrict__ q_h, unsigned short* __restrict__ q_l,
    unsigned short* __restrict__ k_h, unsigned short* __restrict__ k_l,
    unsigned short* __restrict__ v_h, unsigned short* __restrict__ v_l,
    int N, int K) {
  __shared__ short lds[2][16384];
  const int tid = threadIdx.x;
  const int lane = tid & 63;
  const int w = tid >> 6;
  const int wr = w >> 1, wc = w & 1;
  const int bm0 = blockIdx.x * 128;
  const int bn0 = blockIdx.y * 128;

  const unsigned short* srcbase = (w == 0) ? Ahi : (w == 1) ? Alo
                                 : (w == 2) ? Bhi : Blo;
  const int row0 = (w < 2) ? bm0 : bn0;
  const unsigned short* sp =
      srcbase + (size_t)(row0 + (lane & 15)) * K + (lane >> 4) * 8;

  f32x4 acc[4][4];
#pragma unroll
  for (int m = 0; m < 4; ++m)
#pragma unroll
    for (int n = 0; n < 4; ++n) acc[m][n] = (f32x4)0.f;

  // prologue: stage K-tile 0 into buffer 0
#pragma unroll
  for (int g = 0; g < 8; ++g)
    async_copy16(&lds[0][w * 4096 + g * 512], sp + (size_t)g * 16 * K);
  __syncthreads();  // implicit vmcnt(0) drain

  const int nk = K >> 5;
  for (int t = 0; t < nk; ++t) {
    const int cur = t & 1;
    // prefetch next K-tile into the other buffer (issue BEFORE compute)
    if (t + 1 < nk) {
#pragma unroll
      for (int g = 0; g < 8; ++g)
        async_copy16(&lds[cur ^ 1][w * 4096 + g * 512],
                     sp + (size_t)g * 16 * K + (t + 1) * 32);
    }

    const short* lb = &lds[cur][0];
    bf16x8 ah[4], al[4], bh[4], bl[4];
#pragma unroll
    for (int m = 0; m < 4; ++m) {
      ah[m] = *(const bf16x8*)&lb[0 * 4096 + (wr * 4 + m) * 512 + lane * 8];
      al[m] = *(const bf16x8*)&lb[1 * 4096 + (wr * 4 + m) * 512 + lane * 8];
    }
#pragma unroll
    for (int n = 0; n < 4; ++n) {
      bh[n] = *(const bf16x8*)&lb[2 * 4096 + (wc * 4 + n) * 512 + lane * 8];
      bl[n] = *(const bf16x8*)&lb[3 * 4096 + (wc * 4 + n) * 512 + lane * 8];
    }
#pragma unroll
    for (int m = 0; m < 4; ++m)
#pragma unroll
      for (int n = 0; n < 4; ++n) {
        acc[m][n] = __builtin_amdgcn_mfma_f32_16x16x32_bf16(ah[m], bh[n], acc[m][n], 0, 0, 0);
        acc[m][n] = __builtin_amdgcn_mfma_f32_16x16x32_bf16(ah[m], bl[n], acc[m][n], 0, 0, 0);
        acc[m][n] = __builtin_amdgcn_mfma_f32_16x16x32_bf16(al[m], bh[n], acc[m][n], 0, 0, 0);
      }
    // drain prefetch (vmcnt(0)) + ensure all waves done reading buf[cur]
    __syncthreads();
  }

  const int rq = lane >> 4;
  const int cl = lane & 15;
#pragma unroll
  for (int n = 0; n < 4; ++n) {
    const int gn = bn0 + wc * 64 + n * 16 + cl;
    const float bv = bias[gn];
    if (MODE == 0) {
      const int which = gn >> 10;
      const int hh = (gn >> 6) & 15;
      const int d = gn & 63;
      const float scale = (which == 0) ? 0.125f : 1.0f;
      unsigned short* dsth = (which == 0) ? q_h : (which == 1) ? k_h : v_h;
      unsigned short* dstl = (which == 0) ? q_l : (which == 1) ? k_l : v_l;
#pragma unroll
      for (int m = 0; m < 4; ++m)
#pragma unroll
        for (int j = 0; j < 4; ++j) {
          const int gm = bm0 + wr * 64 + m * 16 + rq * 4 + j;
          const int b = gm >> 13;
          const int s = gm & 8191;
          float val = (acc[m][n][j] + bv) * scale;
          unsigned int u = __builtin_bit_cast(unsigned int, val);
          float lf = val - __builtin_bit_cast(float, u & 0xFFFF0000u);
          size_t off = ((size_t)(b * NH + hh) * S_LEN + s) * DH + d;
          dsth[off] = (unsigned short)(u >> 16);
          dstl[off] = (unsigned short)(__builtin_bit_cast(unsigned int, lf) >> 16);
        }
    } else {
#pragma unroll
      for (int m = 0; m < 4; ++m)
#pragma unroll
        for (int j = 0; j < 4; ++j) {
          const int gm = bm0 + wr * 64 + m * 16 + rq * 4 + j;
          Cf[(size_t)gm * N + gn] = acc[m][n][j] + bv;
        }
    }
  }
}

// ---------------------------------------------------------------------------
// MFMA flash attention, split bf16 (hh+hl+lh), swapped QK^T.
// Block = (b, h, group, 256-q chunk); 4 waves x 64 q-rows; KV tiles of 64.
// K staged via pre-swizzled-source global_load_lds; V transposed at staging.
// P repacked C-layout -> B-frag purely with shuffles (no LDS round trip).
// ---------------------------------------------------------------------------
__global__ __launch_bounds__(256, 2) void mattn_kernel(
    const unsigned short* __restrict__ qhi, const unsigned short* __restrict__ qlo,
    const unsigned short* __restrict__ khi, const unsigned short* __restrict__ klo,
    const unsigned short* __restrict__ vhi, const unsigned short* __restrict__ vlo,
    const int* __restrict__ idx,
    unsigned short* __restrict__ ohi, unsigned short* __restrict__ olo) {
  // LDS: Khi [0,8K) Klo [8K,16K) VhiT [16K,24K) VloT [24K,32K) idxg [32K,36K)
  // K/V rows 128B, XOR swizzle byte ^= (row&7)<<4
  __shared__ __align__(16) char smem[36864];
  int* idxg = (int*)(smem + 32768);

  const int tid = threadIdx.x;
  const int lane = tid & 63;
  const int w = tid >> 6;
  const int g = lane >> 4;
  const int q = lane & 15;

  const int c = blockIdx.x;
  const int bh = blockIdx.y;
  const int bb = bh >> 4;
  const int h = bh & 15;
  int gbase, glen, q0;
  if (c < 4) { gbase = 0; glen = 1024; q0 = c * 256; }
  else { int t = c - 4; gbase = 1024 + (t >> 1) * 512; glen = 512; q0 = (t & 1) * 256; }

  for (int i = tid; i < glen; i += 256) idxg[i] = idx[gbase + i];
  __syncthreads();

  const size_t bhoff = (size_t)(bb * NH + h) * S_LEN * DH;
  const unsigned short* qhb = qhi + bhoff;
  const unsigned short* qlb = qlo + bhoff;
  const unsigned short* khb = khi + bhoff;
  const unsigned short* klb = klo + bhoff;
  const unsigned short* vhb = vhi + bhoff;
  const unsigned short* vlb = vlo + bhoff;

  int qrow[4];
#pragma unroll
  for (int qt = 0; qt < 4; ++qt) qrow[qt] = idxg[q0 + w * 64 + qt * 16 + q];

  f32x4 oacc[4][4];
#pragma unroll
  for (int dt = 0; dt < 4; ++dt)
#pragma unroll
    for (int qt = 0; qt < 4; ++qt) oacc[dt][qt] = (f32x4)0.f;
  float mq[4] = {-1e30f, -1e30f, -1e30f, -1e30f};
  float lq[4] = {0.f, 0.f, 0.f, 0.f};

  const int nt = glen >> 6;
  for (int kt_ = 0; kt_ < nt; ++kt_) {
    const int kt0 = kt_ * 64;
    __syncthreads();  // previous tile's LDS reads done

    // --- stage K: 4 global_load_lds per wave, source pre-swizzled ---
#pragma unroll
    for (int ii = 0; ii < 4; ++ii) {
      int i = w * 4 + ii;
      const unsigned short* ka = (i < 8) ? khb : klb;
      int ldsb = (i < 8) ? 0 : 8192;
      int g8 = i & 7;
      int r = g8 * 8 + (lane >> 3);
      int bsw = (lane & 7) ^ (r & 7);
      async_copy16(smem + ldsb + g8 * 1024,
                   ka + (size_t)idxg[kt0 + r] * DH + bsw * 8);
    }
    // --- stage V^T: reg load, pack k-pairs to u32, swizzled ds_write ---
    {
      const unsigned short* va = (tid < 128) ? vhb : vlb;
      char* vbase = smem + 16384 + ((tid < 128) ? 0 : 8192);
      int rem = tid & 127;
      int p = rem & 31;
      int dh = (rem >> 5) * 16;
      int r0 = idxg[kt0 + 2 * p], r1 = idxg[kt0 + 2 * p + 1];
      bf16x8 A0 = *(const bf16x8*)(va + (size_t)r0 * DH + dh);
      bf16x8 A1 = *(const bf16x8*)(va + (size_t)r0 * DH + dh + 8);
      bf16x8 B0 = *(const bf16x8*)(va + (size_t)r1 * DH + dh);
      bf16x8 B1 = *(const bf16x8*)(va + (size_t)r1 * DH + dh + 8);
#pragma unroll
      for (int u = 0; u < 16; ++u) {
        unsigned short a = (unsigned short)((u < 8) ? A0[u] : A1[u - 8]);
        unsigned short b2 = (unsigned short)((u < 8) ? B0[u] : B1[u - 8]);
        unsigned int w32 = (unsigned int)a | ((unsigned int)b2 << 16);
        int d = dh + u;
        int byte_ = (d * 128 + p * 4) ^ ((d & 7) << 4);
        *(unsigned int*)(vbase + byte_) = w32;
      }
    }
    __syncthreads();  // staging visible

    // --- S^T = mfma(K, Q): lane holds q=lane&15, k = kt*16 + 4g + j ---
    f32x4 sacc[4][4];
#pragma unroll
    for (int qt = 0; qt < 4; ++qt)
#pragma unroll
      for (int kt = 0; kt < 4; ++kt) sacc[qt][kt] = (f32x4)0.f;
#pragma unroll
    for (int dc = 0; dc < 2; ++dc) {
      bf16x8 kh[4], kl[4];
#pragma unroll
      for (int kt = 0; kt < 4; ++kt) {
        int r = q + 16 * kt;
        int byte_ = (r * 128 + g * 16 + dc * 64) ^ ((r & 7) << 4);
        kh[kt] = *(const bf16x8*)(smem + byte_);
        kl[kt] = *(const bf16x8*)(smem + 8192 + byte_);
      }
#pragma unroll
      for (int qt = 0; qt < 4; ++qt) {
        bf16x8 qhf = *(const bf16x8*)(qhb + (size_t)qrow[qt] * DH + dc * 32 + g * 8);
        bf16x8 qlf = *(const bf16x8*)(qlb + (size_t)qrow[qt] * DH + dc * 32 + g * 8);
#pragma unroll
        for (int kt = 0; kt < 4; ++kt) {
          sacc[qt][kt] = __builtin_amdgcn_mfma_f32_16x16x32_bf16(kh[kt], qhf, sacc[qt][kt], 0, 0, 0);
          sacc[qt][kt] = __builtin_amdgcn_mfma_f32_16x16x32_bf16(kh[kt], qlf, sacc[qt][kt], 0, 0, 0);
          sacc[qt][kt] = __builtin_amdgcn_mfma_f32_16x16x32_bf16(kl[kt], qhf, sacc[qt][kt], 0, 0, 0);
        }
      }
    }

    // --- online softmax + truncation hi/lo pack + shuffle repack ---
    i32x4 pfh[4][2], pfl[4][2];
#pragma unroll
    for (int qt = 0; qt < 4; ++qt) {
      float mold = mq[qt];
      float tm = -1e30f;
#pragma unroll
      for (int kt = 0; kt < 4; ++kt)
#pragma unroll
        for (int j = 0; j < 4; ++j) tm = fmaxf(tm, sacc[qt][kt][j]);
      tm = fmaxf(tm, __shfl_xor(tm, 16));
      tm = fmaxf(tm, __shfl_xor(tm, 32));
      float mn = fmaxf(mold, tm);
      float su = 0.f;
#pragma unroll
      for (int kt = 0; kt < 4; ++kt)
#pragma unroll
        for (int j = 0; j < 4; ++j) {
          float pv = __expf(sacc[qt][kt][j] - mn);
          sacc[qt][kt][j] = pv;
          su += pv;
        }
      su += __shfl_xor(su, 16);
      su += __shfl_xor(su, 32);
      float rs = __expf(mold - mn);
      lq[qt] = lq[qt] * rs + su;
      mq[qt] = mn;
      if (__any(mn > mold)) {
#pragma unroll
        for (int dt = 0; dt < 4; ++dt) oacc[dt][qt] *= rs;
      }
      unsigned int eh[4][2], el[4][2];
#pragma unroll
      for (int kt = 0; kt < 4; ++kt)
#pragma unroll
        for (int p = 0; p < 2; ++p) {
          float a = sacc[qt][kt][2 * p], b2 = sacc[qt][kt][2 * p + 1];
          unsigned int ua = __builtin_bit_cast(unsigned int, a);
          unsigned int ub = __builtin_bit_cast(unsigned int, b2);
          eh[kt][p] = (ua >> 16) | (ub & 0xFFFF0000u);
          float la = a - __builtin_bit_cast(float, ua & 0xFFFF0000u);
          float lb = b2 - __builtin_bit_cast(float, ub & 0xFFFF0000u);
          el[kt][p] = (__builtin_bit_cast(unsigned int, la) >> 16) |
                      (__builtin_bit_cast(unsigned int, lb) & 0xFFFF0000u);
        }
      // C-layout -> B-frag: dest k' = 8g + j; src kt = 2kc + (g>>1),
      // src lane = q + 32*(g&1) + 16*(t>>1), pair p = t&1.
#pragma unroll
      for (int kc = 0; kc < 2; ++kc) {
        i32x4 fh, fl;
#pragma unroll
        for (int t = 0; t < 4; ++t) {
          int src = q + 32 * (g & 1) + 16 * (t >> 1);
          int ah = __shfl((int)eh[2 * kc][t & 1], src);
          int bh2 = __shfl((int)eh[2 * kc + 1][t & 1], src);
          int al = __shfl((int)el[2 * kc][t & 1], src);
          int bl2 = __shfl((int)el[2 * kc + 1][t & 1], src);
          fh[t] = (g >> 1) ? bh2 : ah;
          fl[t] = (g >> 1) ? bl2 : al;
        }
        pfh[qt][kc] = fh;
        pfl[qt][kc] = fl;
      }
    }

    // --- O^T += mfma(V^T, P) ---
#pragma unroll
    for (int kc = 0; kc < 2; ++kc)
#pragma unroll
      for (int dt = 0; dt < 4; ++dt) {
        int r = q + 16 * dt;
        int byte_ = (r * 128 + g * 16 + kc * 64) ^ ((r & 7) << 4);
        bf16x8 vh = *(const bf16x8*)(smem + 16384 + byte_);
        bf16x8 vl = *(const bf16x8*)(smem + 24576 + byte_);
#pragma unroll
        for (int qt = 0; qt < 4; ++qt) {
          bf16x8 ph = __builtin_bit_cast(bf16x8, pfh[qt][kc]);
          bf16x8 pl = __builtin_bit_cast(bf16x8, pfl[qt][kc]);
          oacc[dt][qt] = __builtin_amdgcn_mfma_f32_16x16x32_bf16(vh, ph, oacc[dt][qt], 0, 0, 0);
          oacc[dt][qt] = __builtin_amdgcn_mfma_f32_16x16x32_bf16(vh, pl, oacc[dt][qt], 0, 0, 0);
          oacc[dt][qt] = __builtin_amdgcn_mfma_f32_16x16x32_bf16(vl, ph, oacc[dt][qt], 0, 0, 0);
        }
      }
  }

  // --- epilogue: normalize, split hi/lo, scatter to (B,S,E) ---
#pragma unroll
  for (int qt = 0; qt < 4; ++qt) {
    float inv = 1.f / lq[qt];
    size_t obase = ((size_t)bb * S_LEN + qrow[qt]) * EE + h * DH;
#pragma unroll
    for (int dt = 0; dt < 4; ++dt) {
      u16x4 hv, lv;
#pragma unroll
      for (int j = 0; j < 4; ++j) {
        float val = oacc[dt][qt][j] * inv;
        unsigned int u = __builtin_bit_cast(unsigned int, val);
        hv[j] = (unsigned short)(u >> 16);
        float lf = val - __builtin_bit_cast(float, u & 0xFFFF0000u);
        lv[j] = (unsigned short)(__builtin_bit_cast(unsigned int, lf) >> 16);
      }
      *(u16x4*)(ohi + obase + dt * 16 + g * 4) = hv;
      *(u16x4*)(olo + obase + dt * 16 + g * 4) = lv;
    }
  }
}

// ---------------------------------------------------------------------------
extern "C" void kernel_launch(void* const* d_in, const int* in_sizes, int n_in,
                              void* d_out, int out_size, void* d_ws, size_t ws_size,
                              hipStream_t stream) {
  const float* x     = (const float*)d_in[0];
  const float* w_qkv = (const float*)d_in[1];
  const float* b_qkv = (const float*)d_in[2];
  const float* w_out = (const float*)d_in[3];
  const float* b_out = (const float*)d_in[4];
  float* outp = (float*)d_out;

  const size_t per = (size_t)BB * S_LEN * EE;  // 16,777,216
  const size_t nwq = (size_t)3 * EE * EE;
  const size_t nwo = (size_t)EE * EE;

  unsigned short* khi = (unsigned short*)d_ws;
  unsigned short* klo = khi + per;
  unsigned short* vhi = klo + per;
  unsigned short* vlo = vhi + per;
  unsigned short* xhi = vlo + per;
  unsigned short* xlo = xhi + per;
  unsigned short* wqh = xlo + per;
  unsigned short* wql = wqh + nwq;
  unsigned short* woh = wql + nwq;
  unsigned short* wol = woh + nwo;
  int* idx = (int*)(wol + nwo);

  unsigned short* qhi = (unsigned short*)d_out;  // q lives in d_out until GEMM2
  unsigned short* qlo = qhi + per;
  unsigned short* ahi = xhi;  // x dead after GEMM1; reuse for attn output
  unsigned short* alo = xlo;

  build_idx_kernel<<<4, 256, 0, stream>>>(idx);
  split_kernel<<<(int)(per / 2048), 256, 0, stream>>>(x, xhi, xlo, (int)per);
  split_kernel<<<(int)(nwq / 2048), 256, 0, stream>>>(w_qkv, wqh, wql, (int)nwq);
  split_kernel<<<(int)(nwo / 2048), 256, 0, stream>>>(w_out, woh, wol, (int)nwo);

  mgemm_kernel<0><<<dim3(128, 24), 256, 0, stream>>>(
      xhi, xlo, wqh, wql, b_qkv, nullptr,
      qhi, qlo, khi, klo, vhi, vlo, 3 * EE, EE);
  mattn_kernel<<<dim3(32, 32), 256, 0, stream>>>(
      qhi, qlo, khi, klo, vhi, vlo, idx, ahi, alo);
  mgemm_kernel<1><<<dim3(128, 8), 256, 0, stream>>>(
      ahi, alo, woh, wol, b_out, outp,
      nullptr, nullptr, nullptr, nullptr, nullptr, nullptr, EE, EE);
}

// Round 5
// 803.669 us; speedup vs baseline: 2.8421x; 1.1674x over previous
//
#include <hip/hip_runtime.h>
#include <hip/hip_bf16.h>
#include <math.h>

#define S_LEN 8192
#define NH 16
#define DH 64
#define BB 2
#define EE 1024

typedef float floatx4 __attribute__((ext_vector_type(4)));
typedef float f32x4 __attribute__((ext_vector_type(4)));
typedef short bf16x8 __attribute__((ext_vector_type(8)));
typedef _Float16 f16x8 __attribute__((ext_vector_type(8)));
typedef int i32x4 __attribute__((ext_vector_type(4)));
typedef unsigned short u16x4 __attribute__((ext_vector_type(4)));

__device__ inline unsigned short f2bf(float x) {
  unsigned int u = __builtin_bit_cast(unsigned int, x);
  u += 0x7FFFu + ((u >> 16) & 1u);
  return (unsigned short)(u >> 16);
}
__device__ inline float bf2f(unsigned short h) {
  return __builtin_bit_cast(float, (unsigned int)h << 16);
}

__device__ inline void async_copy16(void* lds, const void* g) {
  __builtin_amdgcn_global_load_lds(
      (const __attribute__((address_space(1))) void*)g,
      (__attribute__((address_space(3))) void*)lds, 16, 0, 0);
}

// ---------------------------------------------------------------------------
// Hilbert curve d-index (matches reference _xy2d).
// ---------------------------------------------------------------------------
__device__ inline int hilbert_xy2d(int n, int x, int y) {
  int d = 0;
  for (int s = n >> 1; s > 0; s >>= 1) {
    int rx = (x & s) ? 1 : 0;
    int ry = (y & s) ? 1 : 0;
    d += s * s * ((3 * rx) ^ ry);
    if (ry == 0) {
      if (rx == 1) { x = s - 1 - x; y = s - 1 - y; }
      int t = x; x = y; y = t;
    }
  }
  return d;
}

__global__ void build_idx_kernel(int* __restrict__ idx) {
  __shared__ int order[4096];
  __shared__ int perm[4096];
  __shared__ int cnts[256];
  const int seg = blockIdx.x;
  const int posA[4] = {0, 1024, 2048, 4096};
  const int LA[4]   = {1024, 1024, 2048, 4096};
  const int pos = posA[seg];
  const int L = LA[seg];
  const int lr = seg;  // log2(rate)
  const int side  = (L <= 1024) ? 32 : 64;
  const int lside = (L <= 1024) ? 5 : 6;
  const int cells = side * side;
  const int tid = threadIdx.x;

  for (int c = tid; c < cells; c += 256) {
    int x = c & (side - 1);
    int y = c >> lside;
    order[hilbert_xy2d(side, x, y)] = c;
  }
  __syncthreads();

  if (L == cells) {
    for (int t = tid; t < L; t += 256) perm[t] = order[t];
  } else {
    const int per = cells >> 8;  // 16
    const int base = tid * per;
    int cnt = 0;
    for (int u = 0; u < per; ++u) cnt += (order[base + u] < L) ? 1 : 0;
    cnts[tid] = cnt;
    __syncthreads();
    if (tid == 0) {
      int s = 0;
      for (int i = 0; i < 256; ++i) { int c0 = cnts[i]; cnts[i] = s; s += c0; }
    }
    __syncthreads();
    int r = cnts[tid];
    for (int u = 0; u < per; ++u) {
      int o = order[base + u];
      if (o < L) perm[r++] = o;
    }
  }
  __syncthreads();

  const int g = L >> lr;
  const int rm = (1 << lr) - 1;
  for (int t = tid; t < L; t += 256) {
    int j = t & rm;
    int i = t >> lr;
    idx[pos + j * g + i] = pos + perm[t];
  }
}

// ---------------------------------------------------------------------------
// PAIR=1: fp32 -> fp16 hi + fp16 lo (residual). PAIR=0: fp32 -> fp16 round.
// ---------------------------------------------------------------------------
template<int PAIR>
__global__ __launch_bounds__(256) void splitf16_kernel(
    const float* __restrict__ in, unsigned short* __restrict__ hi,
    unsigned short* __restrict__ lo, int n) {
  int base = (blockIdx.x * 256 + threadIdx.x) * 8;
  if (base >= n) return;
  floatx4 v0 = *(const floatx4*)(in + base);
  floatx4 v1 = *(const floatx4*)(in + base + 4);
  u16x4 h0, h1, l0, l1;
#pragma unroll
  for (int i = 0; i < 4; ++i) {
    _Float16 ha = (_Float16)v0[i];
    _Float16 hb = (_Float16)v1[i];
    h0[i] = __builtin_bit_cast(unsigned short, ha);
    h1[i] = __builtin_bit_cast(unsigned short, hb);
    if (PAIR) {
      _Float16 la = (_Float16)(v0[i] - (float)ha);
      _Float16 lb = (_Float16)(v1[i] - (float)hb);
      l0[i] = __builtin_bit_cast(unsigned short, la);
      l1[i] = __builtin_bit_cast(unsigned short, lb);
    }
  }
  *(u16x4*)(hi + base) = h0;
  *(u16x4*)(hi + base + 4) = h1;
  if (PAIR) {
    *(u16x4*)(lo + base) = l0;
    *(u16x4*)(lo + base + 4) = l1;
  }
}

// ---------------------------------------------------------------------------
// fp16 2-term split MFMA GEMM: C = A(MxK) @ B(NxK)^T + bias.
// A = fp16 hi + fp16 lo (exact to 2^-22), B = single fp16 (err 2^-11).
// 128x128 tile, BK=32, 4 waves (2x2), fragment-linear LDS, DEPTH-3 pipeline
// with counted vmcnt(6) + raw s_barrier (loads span 2 iterations; never
// drained to 0 in the steady loop). 32 f16-MFMA + 12 ds_read_b128 per step.
// MODE 0: split hi/lo bf16 scatter into q/k/v (B,H,S,D); q pre-scaled 0.125.
// MODE 1: plain row-major fp32 C.
// ---------------------------------------------------------------------------
template<int MODE>
__global__ __launch_bounds__(256) void mgemm_kernel(
    const unsigned short* __restrict__ Ahi, const unsigned short* __restrict__ Alo,
    const unsigned short* __restrict__ Bh,
    const float* __restrict__ bias, float* __restrict__ Cf,
    unsigned short* __restrict__ q_h, unsigned short* __restrict__ q_l,
    unsigned short* __restrict__ k_h, unsigned short* __restrict__ k_l,
    unsigned short* __restrict__ v_h, unsigned short* __restrict__ v_l,
    int N, int K) {
  // 3 pipeline buffers x (Ahi 8KB | Alo 8KB | Bh 8KB) = 72 KB
  __shared__ short lds[3][12288];
  const int tid = threadIdx.x;
  const int lane = tid & 63;
  const int w = tid >> 6;
  const int wr = w >> 1, wc = w & 1;
  const int bm0 = blockIdx.x * 128;
  const int bn0 = blockIdx.y * 128;

  // staging: 24 groups (tile = e>>3: 0 Ahi, 1 Alo, 2 Bh; g = e&7), 6 per wave
  const unsigned short* sp[6];
  int dofs[6];
#pragma unroll
  for (int ii = 0; ii < 6; ++ii) {
    int e = w * 6 + ii;
    int tile = e >> 3;
    int g = e & 7;
    const unsigned short* base = (tile == 0) ? Ahi : (tile == 1) ? Alo : Bh;
    int row0 = (tile < 2) ? bm0 : bn0;
    sp[ii] = base + (size_t)(row0 + g * 16 + (lane & 15)) * K + (lane >> 4) * 8;
    dofs[ii] = tile * 4096 + g * 512;
  }

  f32x4 acc[4][4];
#pragma unroll
  for (int m = 0; m < 4; ++m)
#pragma unroll
    for (int n = 0; n < 4; ++n) acc[m][n] = (f32x4)0.f;

  const int nk = K >> 5;
  // prologue: stage tiles 0 and 1
#pragma unroll
  for (int ii = 0; ii < 6; ++ii) async_copy16(&lds[0][dofs[ii]], sp[ii]);
#pragma unroll
  for (int ii = 0; ii < 6; ++ii) async_copy16(&lds[1][dofs[ii]], sp[ii] + 32);
  asm volatile("s_waitcnt vmcnt(6)" ::: "memory");  // tile 0 landed
  __builtin_amdgcn_s_barrier();

  for (int t = 0; t < nk; ++t) {
    const short* lb = &lds[0][0] + (t % 3) * 12288;
    if (t + 2 < nk) {
      const int k0 = (t + 2) * 32;
      short* db = &lds[0][0] + ((t + 2) % 3) * 12288;
#pragma unroll
      for (int ii = 0; ii < 6; ++ii) async_copy16(db + dofs[ii], sp[ii] + k0);
    }

    f16x8 ah[4], al[4], bf[4];
#pragma unroll
    for (int m = 0; m < 4; ++m) {
      ah[m] = *(const f16x8*)&lb[(wr * 4 + m) * 512 + lane * 8];
      al[m] = *(const f16x8*)&lb[4096 + (wr * 4 + m) * 512 + lane * 8];
    }
#pragma unroll
    for (int n = 0; n < 4; ++n)
      bf[n] = *(const f16x8*)&lb[8192 + (wc * 4 + n) * 512 + lane * 8];

    __builtin_amdgcn_s_setprio(1);
#pragma unroll
    for (int m = 0; m < 4; ++m)
#pragma unroll
      for (int n = 0; n < 4; ++n) {
        acc[m][n] = __builtin_amdgcn_mfma_f32_16x16x32_f16(ah[m], bf[n], acc[m][n], 0, 0, 0);
        acc[m][n] = __builtin_amdgcn_mfma_f32_16x16x32_f16(al[m], bf[n], acc[m][n], 0, 0, 0);
      }
    __builtin_amdgcn_s_setprio(0);

    // wait tile t+1 (issued one iteration ago); keep t+2's 6 loads in flight
    if (t + 2 < nk) {
      asm volatile("s_waitcnt vmcnt(6)" ::: "memory");
    } else {
      asm volatile("s_waitcnt vmcnt(0)" ::: "memory");
    }
    if (t + 1 < nk) __builtin_amdgcn_s_barrier();
  }

  const int rq = lane >> 4;
  const int cl = lane & 15;
#pragma unroll
  for (int n = 0; n < 4; ++n) {
    const int gn = bn0 + wc * 64 + n * 16 + cl;
    const float bv = bias[gn];
    if (MODE == 0) {
      const int which = gn >> 10;
      const int hh = (gn >> 6) & 15;
      const int d = gn & 63;
      const float scale = (which == 0) ? 0.125f : 1.0f;
      unsigned short* dsth = (which == 0) ? q_h : (which == 1) ? k_h : v_h;
      unsigned short* dstl = (which == 0) ? q_l : (which == 1) ? k_l : v_l;
#pragma unroll
      for (int m = 0; m < 4; ++m)
#pragma unroll
        for (int j = 0; j < 4; ++j) {
          const int gm = bm0 + wr * 64 + m * 16 + rq * 4 + j;
          const int b = gm >> 13;
          const int s = gm & 8191;
          float val = (acc[m][n][j] + bv) * scale;
          unsigned int u = __builtin_bit_cast(unsigned int, val);
          float lf = val - __builtin_bit_cast(float, u & 0xFFFF0000u);
          size_t off = ((size_t)(b * NH + hh) * S_LEN + s) * DH + d;
          dsth[off] = (unsigned short)(u >> 16);
          dstl[off] = (unsigned short)(__builtin_bit_cast(unsigned int, lf) >> 16);
        }
    } else {
#pragma unroll
      for (int m = 0; m < 4; ++m)
#pragma unroll
        for (int j = 0; j < 4; ++j) {
          const int gm = bm0 + wr * 64 + m * 16 + rq * 4 + j;
          Cf[(size_t)gm * N + gn] = acc[m][n][j] + bv;
        }
    }
  }
}

// ---------------------------------------------------------------------------
// MFMA flash attention, split bf16 (hh+hl+lh), swapped QK^T.
// Block = (b, h, group, 256-q chunk); 4 waves x 64 q-rows; KV tiles of 64.
// K staged via pre-swizzled-source global_load_lds; V transposed at staging.
// P repacked C-layout -> B-frag purely with shuffles (no LDS round trip).
// Epilogue emits fp16 hi/lo for GEMM2.
// ---------------------------------------------------------------------------
__global__ __launch_bounds__(256, 2) void mattn_kernel(
    const unsigned short* __restrict__ qhi, const unsigned short* __restrict__ qlo,
    const unsigned short* __restrict__ khi, const unsigned short* __restrict__ klo,
    const unsigned short* __restrict__ vhi, const unsigned short* __restrict__ vlo,
    const int* __restrict__ idx,
    unsigned short* __restrict__ ohi, unsigned short* __restrict__ olo) {
  // LDS: Khi [0,8K) Klo [8K,16K) VhiT [16K,24K) VloT [24K,32K) idxg [32K,36K)
  // K/V rows 128B, XOR swizzle byte ^= (row&7)<<4
  __shared__ __align__(16) char smem[36864];
  int* idxg = (int*)(smem + 32768);

  const int tid = threadIdx.x;
  const int lane = tid & 63;
  const int w = tid >> 6;
  const int g = lane >> 4;
  const int q = lane & 15;

  const int c = blockIdx.x;
  const int bh = blockIdx.y;
  const int bb = bh >> 4;
  const int h = bh & 15;
  int gbase, glen, q0;
  if (c < 4) { gbase = 0; glen = 1024; q0 = c * 256; }
  else { int t = c - 4; gbase = 1024 + (t >> 1) * 512; glen = 512; q0 = (t & 1) * 256; }

  for (int i = tid; i < glen; i += 256) idxg[i] = idx[gbase + i];
  __syncthreads();

  const size_t bhoff = (size_t)(bb * NH + h) * S_LEN * DH;
  const unsigned short* qhb = qhi + bhoff;
  const unsigned short* qlb = qlo + bhoff;
  const unsigned short* khb = khi + bhoff;
  const unsigned short* klb = klo + bhoff;
  const unsigned short* vhb = vhi + bhoff;
  const unsigned short* vlb = vlo + bhoff;

  int qrow[4];
#pragma unroll
  for (int qt = 0; qt < 4; ++qt) qrow[qt] = idxg[q0 + w * 64 + qt * 16 + q];

  f32x4 oacc[4][4];
#pragma unroll
  for (int dt = 0; dt < 4; ++dt)
#pragma unroll
    for (int qt = 0; qt < 4; ++qt) oacc[dt][qt] = (f32x4)0.f;
  float mq[4] = {-1e30f, -1e30f, -1e30f, -1e30f};
  float lq[4] = {0.f, 0.f, 0.f, 0.f};

  const int nt = glen >> 6;
  for (int kt_ = 0; kt_ < nt; ++kt_) {
    const int kt0 = kt_ * 64;
    __syncthreads();  // previous tile's LDS reads done

    // --- stage K: 4 global_load_lds per wave, source pre-swizzled ---
#pragma unroll
    for (int ii = 0; ii < 4; ++ii) {
      int i = w * 4 + ii;
      const unsigned short* ka = (i < 8) ? khb : klb;
      int ldsb = (i < 8) ? 0 : 8192;
      int g8 = i & 7;
      int r = g8 * 8 + (lane >> 3);
      int bsw = (lane & 7) ^ (r & 7);
      async_copy16(smem + ldsb + g8 * 1024,
                   ka + (size_t)idxg[kt0 + r] * DH + bsw * 8);
    }
    // --- stage V^T: reg load, pack k-pairs to u32, swizzled ds_write ---
    {
      const unsigned short* va = (tid < 128) ? vhb : vlb;
      char* vbase = smem + 16384 + ((tid < 128) ? 0 : 8192);
      int rem = tid & 127;
      int p = rem & 31;
      int dh = (rem >> 5) * 16;
      int r0 = idxg[kt0 + 2 * p], r1 = idxg[kt0 + 2 * p + 1];
      bf16x8 A0 = *(const bf16x8*)(va + (size_t)r0 * DH + dh);
      bf16x8 A1 = *(const bf16x8*)(va + (size_t)r0 * DH + dh + 8);
      bf16x8 B0 = *(const bf16x8*)(va + (size_t)r1 * DH + dh);
      bf16x8 B1 = *(const bf16x8*)(va + (size_t)r1 * DH + dh + 8);
#pragma unroll
      for (int u = 0; u < 16; ++u) {
        unsigned short a = (unsigned short)((u < 8) ? A0[u] : A1[u - 8]);
        unsigned short b2 = (unsigned short)((u < 8) ? B0[u] : B1[u - 8]);
        unsigned int w32 = (unsigned int)a | ((unsigned int)b2 << 16);
        int d = dh + u;
        int byte_ = (d * 128 + p * 4) ^ ((d & 7) << 4);
        *(unsigned int*)(vbase + byte_) = w32;
      }
    }
    __syncthreads();  // staging visible

    // --- S^T = mfma(K, Q): lane holds q=lane&15, k = kt*16 + 4g + j ---
    f32x4 sacc[4][4];
#pragma unroll
    for (int qt = 0; qt < 4; ++qt)
#pragma unroll
      for (int kt = 0; kt < 4; ++kt) sacc[qt][kt] = (f32x4)0.f;
#pragma unroll
    for (int dc = 0; dc < 2; ++dc) {
      bf16x8 kh[4], kl[4];
#pragma unroll
      for (int kt = 0; kt < 4; ++kt) {
        int r = q + 16 * kt;
        int byte_ = (r * 128 + g * 16 + dc * 64) ^ ((r & 7) << 4);
        kh[kt] = *(const bf16x8*)(smem + byte_);
        kl[kt] = *(const bf16x8*)(smem + 8192 + byte_);
      }
#pragma unroll
      for (int qt = 0; qt < 4; ++qt) {
        bf16x8 qhf = *(const bf16x8*)(qhb + (size_t)qrow[qt] * DH + dc * 32 + g * 8);
        bf16x8 qlf = *(const bf16x8*)(qlb + (size_t)qrow[qt] * DH + dc * 32 + g * 8);
#pragma unroll
        for (int kt = 0; kt < 4; ++kt) {
          sacc[qt][kt] = __builtin_amdgcn_mfma_f32_16x16x32_bf16(kh[kt], qhf, sacc[qt][kt], 0, 0, 0);
          sacc[qt][kt] = __builtin_amdgcn_mfma_f32_16x16x32_bf16(kh[kt], qlf, sacc[qt][kt], 0, 0, 0);
          sacc[qt][kt] = __builtin_amdgcn_mfma_f32_16x16x32_bf16(kl[kt], qhf, sacc[qt][kt], 0, 0, 0);
        }
      }
    }

    // --- online softmax + truncation hi/lo pack + shuffle repack ---
    i32x4 pfh[4][2], pfl[4][2];
#pragma unroll
    for (int qt = 0; qt < 4; ++qt) {
      float mold = mq[qt];
      float tm = -1e30f;
#pragma unroll
      for (int kt = 0; kt < 4; ++kt)
#pragma unroll
        for (int j = 0; j < 4; ++j) tm = fmaxf(tm, sacc[qt][kt][j]);
      tm = fmaxf(tm, __shfl_xor(tm, 16));
      tm = fmaxf(tm, __shfl_xor(tm, 32));
      float mn = fmaxf(mold, tm);
      float su = 0.f;
#pragma unroll
      for (int kt = 0; kt < 4; ++kt)
#pragma unroll
        for (int j = 0; j < 4; ++j) {
          float pv = __expf(sacc[qt][kt][j] - mn);
          sacc[qt][kt][j] = pv;
          su += pv;
        }
      su += __shfl_xor(su, 16);
      su += __shfl_xor(su, 32);
      float rs = __expf(mold - mn);
      lq[qt] = lq[qt] * rs + su;
      mq[qt] = mn;
      if (__any(mn > mold)) {
#pragma unroll
        for (int dt = 0; dt < 4; ++dt) oacc[dt][qt] *= rs;
      }
      unsigned int eh[4][2], el[4][2];
#pragma unroll
      for (int kt = 0; kt < 4; ++kt)
#pragma unroll
        for (int p = 0; p < 2; ++p) {
          float a = sacc[qt][kt][2 * p], b2 = sacc[qt][kt][2 * p + 1];
          unsigned int ua = __builtin_bit_cast(unsigned int, a);
          unsigned int ub = __builtin_bit_cast(unsigned int, b2);
          eh[kt][p] = (ua >> 16) | (ub & 0xFFFF0000u);
          float la = a - __builtin_bit_cast(float, ua & 0xFFFF0000u);
          float lb = b2 - __builtin_bit_cast(float, ub & 0xFFFF0000u);
          el[kt][p] = (__builtin_bit_cast(unsigned int, la) >> 16) |
                      (__builtin_bit_cast(unsigned int, lb) & 0xFFFF0000u);
        }
      // C-layout -> B-frag: dest k' = 8g + j; src kt = 2kc + (g>>1),
      // src lane = q + 32*(g&1) + 16*(t>>1), pair p = t&1.
#pragma unroll
      for (int kc = 0; kc < 2; ++kc) {
        i32x4 fh, fl;
#pragma unroll
        for (int t = 0; t < 4; ++t) {
          int src = q + 32 * (g & 1) + 16 * (t >> 1);
          int ah = __shfl((int)eh[2 * kc][t & 1], src);
          int bh2 = __shfl((int)eh[2 * kc + 1][t & 1], src);
          int al = __shfl((int)el[2 * kc][t & 1], src);
          int bl2 = __shfl((int)el[2 * kc + 1][t & 1], src);
          fh[t] = (g >> 1) ? bh2 : ah;
          fl[t] = (g >> 1) ? bl2 : al;
        }
        pfh[qt][kc] = fh;
        pfl[qt][kc] = fl;
      }
    }

    // --- O^T += mfma(V^T, P) ---
#pragma unroll
    for (int kc = 0; kc < 2; ++kc)
#pragma unroll
      for (int dt = 0; dt < 4; ++dt) {
        int r = q + 16 * dt;
        int byte_ = (r * 128 + g * 16 + kc * 64) ^ ((r & 7) << 4);
        bf16x8 vh = *(const bf16x8*)(smem + 16384 + byte_);
        bf16x8 vl = *(const bf16x8*)(smem + 24576 + byte_);
#pragma unroll
        for (int qt = 0; qt < 4; ++qt) {
          bf16x8 ph = __builtin_bit_cast(bf16x8, pfh[qt][kc]);
          bf16x8 pl = __builtin_bit_cast(bf16x8, pfl[qt][kc]);
          oacc[dt][qt] = __builtin_amdgcn_mfma_f32_16x16x32_bf16(vh, ph, oacc[dt][qt], 0, 0, 0);
          oacc[dt][qt] = __builtin_amdgcn_mfma_f32_16x16x32_bf16(vh, pl, oacc[dt][qt], 0, 0, 0);
          oacc[dt][qt] = __builtin_amdgcn_mfma_f32_16x16x32_bf16(vl, ph, oacc[dt][qt], 0, 0, 0);
        }
      }
  }

  // --- epilogue: normalize, split fp16 hi/lo, scatter to (B,S,E) ---
#pragma unroll
  for (int qt = 0; qt < 4; ++qt) {
    float inv = 1.f / lq[qt];
    size_t obase = ((size_t)bb * S_LEN + qrow[qt]) * EE + h * DH;
#pragma unroll
    for (int dt = 0; dt < 4; ++dt) {
      u16x4 hv, lv;
#pragma unroll
      for (int j = 0; j < 4; ++j) {
        float val = oacc[dt][qt][j] * inv;
        _Float16 hf = (_Float16)val;
        _Float16 lf = (_Float16)(val - (float)hf);
        hv[j] = __builtin_bit_cast(unsigned short, hf);
        lv[j] = __builtin_bit_cast(unsigned short, lf);
      }
      *(u16x4*)(ohi + obase + dt * 16 + g * 4) = hv;
      *(u16x4*)(olo + obase + dt * 16 + g * 4) = lv;
    }
  }
}

// ---------------------------------------------------------------------------
extern "C" void kernel_launch(void* const* d_in, const int* in_sizes, int n_in,
                              void* d_out, int out_size, void* d_ws, size_t ws_size,
                              hipStream_t stream) {
  const float* x     = (const float*)d_in[0];
  const float* w_qkv = (const float*)d_in[1];
  const float* b_qkv = (const float*)d_in[2];
  const float* w_out = (const float*)d_in[3];
  const float* b_out = (const float*)d_in[4];
  float* outp = (float*)d_out;

  const size_t per = (size_t)BB * S_LEN * EE;  // 16,777,216
  const size_t nwq = (size_t)3 * EE * EE;
  const size_t nwo = (size_t)EE * EE;

  unsigned short* khi = (unsigned short*)d_ws;   // bf16 pairs for attention
  unsigned short* klo = khi + per;
  unsigned short* vhi = klo + per;
  unsigned short* vlo = vhi + per;
  unsigned short* xhi = vlo + per;               // fp16 pair of x
  unsigned short* xlo = xhi + per;
  unsigned short* wqh = xlo + per;               // fp16 weights
  unsigned short* woh = wqh + nwq;
  int* idx = (int*)(woh + nwo);

  unsigned short* qhi = (unsigned short*)d_out;  // bf16 q pair in d_out
  unsigned short* qlo = qhi + per;
  unsigned short* ahi = xhi;  // x dead after GEMM1; reuse for attn out (fp16)
  unsigned short* alo = xlo;

  build_idx_kernel<<<4, 256, 0, stream>>>(idx);
  splitf16_kernel<1><<<(int)(per / 2048), 256, 0, stream>>>(x, xhi, xlo, (int)per);
  splitf16_kernel<0><<<(int)(nwq / 2048), 256, 0, stream>>>(w_qkv, wqh, nullptr, (int)nwq);
  splitf16_kernel<0><<<(int)(nwo / 2048), 256, 0, stream>>>(w_out, woh, nullptr, (int)nwo);

  mgemm_kernel<0><<<dim3(128, 24), 256, 0, stream>>>(
      xhi, xlo, wqh, b_qkv, nullptr,
      qhi, qlo, khi, klo, vhi, vlo, 3 * EE, EE);
  mattn_kernel<<<dim3(32, 32), 256, 0, stream>>>(
      qhi, qlo, khi, klo, vhi, vlo, idx, ahi, alo);
  mgemm_kernel<1><<<dim3(128, 8), 256, 0, stream>>>(
      ahi, alo, woh, b_out, outp,
      nullptr, nullptr, nullptr, nullptr, nullptr, nullptr, EE, EE);
}